// Round 12
// baseline (173.042 us; speedup 1.0000x reference)
//
#include <hip/hip_runtime.h>

typedef unsigned short ushort_t;
typedef unsigned int uint_t;
typedef __attribute__((ext_vector_type(4))) float f32x4;
typedef __attribute__((ext_vector_type(8))) __bf16 bf16x8;

#define LAMBDA_INIT 0.7836057665316245f
#define ONE_MINUS_LI 0.21639423346837552f
#define QSCALE_LOG2E 0.25505654442552663f  // 32^-0.5 * log2(e)

__device__ inline ushort_t f2bf(float f) {
  union { float f; unsigned u; } v; v.f = f;
  unsigned r = (v.u + 0x7FFFu + ((v.u >> 16) & 1u)) >> 16;
  return (ushort_t)r;
}

// bare v_exp_f32 (args bounded, no libm range fixup needed)
__device__ inline float fexp2(float x) {
  float r;
  asm("v_exp_f32 %0, %1" : "=v"(r) : "v"(x));
  return r;
}

// pack 2 f32 -> 2 bf16 (RNE), lo in low half
__device__ inline uint_t cvtpk(float lo, float hi) {
  uint_t r;
  asm("v_cvt_pk_bf16_f32 %0, %1, %2" : "=v"(r) : "v"(lo), "v"(hi));
  return r;
}

__device__ inline f32x4 zero4() { f32x4 z = {0.f, 0.f, 0.f, 0.f}; return z; }

__device__ inline f32x4 mfma16(bf16x8 a, bf16x8 b, f32x4 c) {
  return __builtin_amdgcn_mfma_f32_16x16x32_bf16(a, b, c, 0, 0, 0);
}

__device__ inline void gload_lds16(const void* g, void* l) {
  __builtin_amdgcn_global_load_lds(
      (const __attribute__((address_space(1))) unsigned int*)g,
      (__attribute__((address_space(3))) unsigned int*)l, 16, 0, 0);
}

// ---------------- convert x (fp32 -> bf16) ----------------
__global__ __launch_bounds__(256) void cvt_f32_bf16(const float* __restrict__ in,
                                                    ushort_t* __restrict__ out, int n) {
  int i = (blockIdx.x * 256 + threadIdx.x) * 8;
  if (i >= n) return;
  float4 a = *(const float4*)(in + i);
  float4 b = *(const float4*)(in + i + 4);
  uint4 pack;
  pack.x = cvtpk(a.x, a.y);
  pack.y = cvtpk(a.z, a.w);
  pack.z = cvtpk(b.x, b.y);
  pack.w = cvtpk(b.z, b.w);
  *(uint4*)(out + i) = pack;
}

// ---------------- transpose W (KxN fp32) -> WT (NxK bf16) ----------------
__global__ __launch_bounds__(256) void transpose_to_bf16(const float* __restrict__ W,
                                                         ushort_t* __restrict__ WT,
                                                         int K, int N) {
  __shared__ float tile[32][33];
  int n0 = blockIdx.x * 32, k0 = blockIdx.y * 32;
  int tx = threadIdx.x & 31, ty = threadIdx.x >> 5;
#pragma unroll
  for (int j = 0; j < 4; ++j) {
    int k = k0 + ty + j * 8;
    tile[ty + j * 8][tx] = W[(size_t)k * N + n0 + tx];
  }
  __syncthreads();
#pragma unroll
  for (int j = 0; j < 4; ++j) {
    int n = n0 + ty + j * 8;
    WT[(size_t)n * K + k0 + tx] = f2bf(tile[tx][ty + j * 8]);
  }
}

// ---------------- GEMM: C[M,N] = A[M,K] * Bt[N,K]^T, bf16 in ----------------
// XCD-aware block swizzle: XCD r hosts contiguous col-panels -> B reuse in L2.
template <int MODE>
__global__ __launch_bounds__(256) void gemm_bt(const ushort_t* __restrict__ A,
                                               const ushort_t* __restrict__ Bt,
                                               void* __restrict__ C,
                                               ushort_t* __restrict__ vt_out,
                                               const float* __restrict__ bias,
                                               int M, int N, int K) {
  __shared__ ushort_t As[128 * 32];
  __shared__ ushort_t Bs[128 * 32];
  const int tid = threadIdx.x;
  const int wave = tid >> 6, lane = tid & 63;
  const int wr = wave >> 1, wc = wave & 1;
  const int lg = lane >> 4, ll = lane & 15;

  // XCD swizzle (nwg divisible by 8: 768 and 256)
  const int lin = blockIdx.x + gridDim.x * blockIdx.y;
  const int cpx = (gridDim.x * gridDim.y) >> 3;
  const int swz = (lin & 7) * cpx + (lin >> 3);
  const int row0 = (swz % gridDim.x) * 128, col0 = (swz / gridDim.x) * 128;

  f32x4 acc[4][4];
#pragma unroll
  for (int m = 0; m < 4; ++m)
#pragma unroll
    for (int n = 0; n < 4; ++n) acc[m][n] = zero4();

  for (int k0 = 0; k0 < K; k0 += 32) {
    __syncthreads();
#pragma unroll
    for (int i = 0; i < 2; ++i) {
      int c = tid + i * 256;
      int r = c >> 2, ko = (c & 3) << 3;
      gload_lds16(A + (size_t)(row0 + r) * K + k0 + ko,
                  (char*)As + (size_t)(wave * 64 + i * 256) * 16);
      gload_lds16(Bt + (size_t)(col0 + r) * K + k0 + ko,
                  (char*)Bs + (size_t)(wave * 64 + i * 256) * 16);
    }
    __syncthreads();
    bf16x8 af[4], bf[4];
#pragma unroll
    for (int m = 0; m < 4; ++m)
      af[m] = *(const bf16x8*)(As + (wr * 64 + m * 16 + ll) * 32 + (lg << 3));
#pragma unroll
    for (int n = 0; n < 4; ++n)
      bf[n] = *(const bf16x8*)(Bs + (wc * 64 + n * 16 + ll) * 32 + (lg << 3));
#pragma unroll
    for (int m = 0; m < 4; ++m)
#pragma unroll
      for (int n = 0; n < 4; ++n) acc[m][n] = mfma16(af[m], bf[n], acc[m][n]);
  }

#pragma unroll
  for (int m = 0; m < 4; ++m) {
#pragma unroll
    for (int n = 0; n < 4; ++n) {
      int gc = col0 + wc * 64 + n * 16 + ll;
      int gr0 = row0 + wr * 64 + m * 16 + (lg << 2);
      if (MODE == 0) {
#pragma unroll
        for (int j = 0; j < 4; ++j)
          ((float*)C)[(size_t)(gr0 + j) * N + gc] = acc[m][n][j] + bias[gc];
      } else {
        if (gc < 2048) {
          float sc = (gc < 1024) ? QSCALE_LOG2E : 1.0f;
#pragma unroll
          for (int j = 0; j < 4; ++j)
            ((ushort_t*)C)[(size_t)(gr0 + j) * 2048 + gc] = f2bf(acc[m][n][j] * sc);
        } else {
          // V columns -> transposed store, 4 consecutive n packed into 8B
          int hv = (gc - 2048) >> 6, dv = (gc - 2048) & 63;
          int bb = gr0 >> 11, nn = gr0 & 2047;
          uint2 w;
          w.x = cvtpk(acc[m][n][0], acc[m][n][1]);
          w.y = cvtpk(acc[m][n][2], acc[m][n][3]);
          *(uint2*)(vt_out + ((size_t)((bb * 16 + hv) * 64 + dv)) * 2048 + nn) = w;
        }
      }
    }
  }
}

// ---------------- differential flash attention ----------------
// R11 kernel (XCD-swizzled, proven) with V single-buffered: vf is consumed
// into registers at tile start, so Vs is dead during compute -> stage V(t+1)
// into the SAME buffer after a barrier. LDS 41984 -> 33792 B = 4 blocks/CU,
// all 1024 blocks co-resident (kills the 256-block tail phase).
// + T5 s_setprio(1) around MFMA clusters.
__global__ __launch_bounds__(256) void diff_attn(const ushort_t* __restrict__ qk,
                                                 const ushort_t* __restrict__ vt,
                                                 ushort_t* __restrict__ o,
                                                 const float* __restrict__ lq1,
                                                 const float* __restrict__ lk1,
                                                 const float* __restrict__ lq2,
                                                 const float* __restrict__ lk2,
                                                 const float* __restrict__ subln) {
  const int lin = blockIdx.x + (blockIdx.y << 5) + (blockIdx.z << 9);
  const int swz = ((lin & 7) << 7) + (lin >> 3);    // XCD r -> swz in [128r, 128r+128)
  const int qt = swz & 31, h = (swz >> 5) & 15, b = swz >> 9;
  const int tid = threadIdx.x, wave = tid >> 6, lane = tid & 63;
  const int lg = lane >> 4, ll = lane & 15;

  const size_t qbase = (size_t)b * 2048 * 2048;
  const int cq1 = (h << 5), cq2 = 512 + (h << 5);
  const int ck1 = 1024 + (h << 5), ck2 = 1536 + (h << 5);
  const size_t vbase = (size_t)((b * 16 + h) * 64) * 2048;

  float sl1 = 0.f, sl2 = 0.f;
  for (int j = 0; j < 32; ++j) { sl1 += lq1[j] * lk1[j]; sl2 += lq2[j] * lk2[j]; }
  const float lam = __expf(sl1) - __expf(sl2) + LAMBDA_INIT;

  __shared__ ushort_t Ks[2][64 * 64];   // [kv r][8 chunks: 0-3 K1, 4-7 K2], XOR-8 swizzled
  __shared__ ushort_t Vs[64 * 64];      // [d r][8 t-chunks], XOR-8 swizzled, SINGLE buffer
  __shared__ ushort_t Pl[4][16 * 72];   // per-wave P, padded stride 72 (proven affine path)

  // Q fragments (B-operand of swapped QK^T)
  const int qrow = qt * 64 + wave * 16 + ll;
  const bf16x8 q1f = *(const bf16x8*)(qk + qbase + (size_t)qrow * 2048 + cq1 + (lg << 3));
  const bf16x8 q2f = *(const bf16x8*)(qk + qbase + (size_t)qrow * 2048 + cq2 + (lg << 3));

  f32x4 o1[4], o2[4];
#pragma unroll
  for (int nb = 0; nb < 4; ++nb) { o1[nb] = zero4(); o2[nb] = zero4(); }
  float l1p = 0.f, l2p = 0.f;
  ushort_t* Pw = &Pl[wave][0];

  // staging geometry: slot s -> row r = s>>3, lds chunk s&7 holds global chunk (s&7)^(r&7)
  const int s0 = tid, s1 = tid + 256;
  const int r0 = s0 >> 3, c0 = (s0 & 7) ^ (r0 & 7);
  const int r1 = s1 >> 3, c1 = (s1 & 7) ^ (r1 & 7);
  const int kc0 = ((c0 & 4) ? ck2 : ck1) + ((c0 & 3) << 3);
  const int kc1 = ((c1 & 4) ? ck2 : ck1) + ((c1 & 3) << 3);
  const int ub0 = (wave << 6) * 16;
  const int ub1 = ((wave << 6) + 256) * 16;

#define STAGE_K(buf, kv0)                                                                 \
  do {                                                                                    \
    gload_lds16(qk + qbase + (size_t)((kv0) + r0) * 2048 + kc0, (char*)Ks[buf] + ub0);    \
    gload_lds16(qk + qbase + (size_t)((kv0) + r1) * 2048 + kc1, (char*)Ks[buf] + ub1);    \
  } while (0)
#define STAGE_V(kv0)                                                                      \
  do {                                                                                    \
    gload_lds16(vt + vbase + (size_t)r0 * 2048 + (kv0) + (c0 << 3), (char*)Vs + ub0);     \
    gload_lds16(vt + vbase + (size_t)r1 * 2048 + (kv0) + (c1 << 3), (char*)Vs + ub1);     \
  } while (0)

  auto read_vf = [&](bf16x8 (&vf)[2][4]) {
#pragma unroll
    for (int ks = 0; ks < 2; ++ks)
#pragma unroll
      for (int nb = 0; nb < 4; ++nb)
        vf[ks][nb] = *(const bf16x8*)(Vs + nb * 1024 + ll * 64 + (((ks * 4 + lg) ^ (ll & 7)) << 3));
  };

  auto compute_tile = [&](const ushort_t* Kc, const bf16x8 (&vf)[2][4]) {
#pragma unroll
    for (int pass = 0; pass < 2; ++pass) {
      const int cK = (lg ^ (ll & 7)) ^ (pass << 2);
      bf16x8 kf[4];
#pragma unroll
      for (int nb = 0; nb < 4; ++nb)
        kf[nb] = *(const bf16x8*)(Kc + nb * 1024 + ll * 64 + (cK << 3));
      const bf16x8 qf = pass ? q2f : q1f;
      f32x4* oacc = pass ? o2 : o1;
      f32x4 s[4];
      __builtin_amdgcn_s_setprio(1);
#pragma unroll
      for (int nb = 0; nb < 4; ++nb)
        s[nb] = mfma16(kf[nb], qf, zero4());   // D: row=k (4lg+i), col=q (ll)
      __builtin_amdgcn_s_setprio(0);
      float part = 0.f;
#pragma unroll
      for (int nb = 0; nb < 4; ++nb) {
        float e0 = fexp2(s[nb][0]), e1 = fexp2(s[nb][1]);
        float e2 = fexp2(s[nb][2]), e3 = fexp2(s[nb][3]);
        part += (e0 + e1) + (e2 + e3);
        uint2 w;
        w.x = cvtpk(e0, e1);
        w.y = cvtpk(e2, e3);
        // P[q=ll][k = nb*16 + 4lg .. +3]
        *(uint2*)(Pw + ll * 72 + nb * 16 + (lg << 2)) = w;
      }
      if (pass) l2p += part; else l1p += part;
      __builtin_amdgcn_s_setprio(1);
#pragma unroll
      for (int ks = 0; ks < 2; ++ks) {
        bf16x8 pf = *(const bf16x8*)(Pw + ll * 72 + ks * 32 + (lg << 3));
#pragma unroll
        for (int nb = 0; nb < 4; ++nb) oacc[nb] = mfma16(pf, vf[ks][nb], oacc[nb]);
      }
      __builtin_amdgcn_s_setprio(0);
    }
  };

  STAGE_K(0, 0);
  STAGE_V(0);
  __syncthreads();   // tile 0 landed
  for (int it = 0; it < 16; ++it) {
    const int t0 = it * 2;
    bf16x8 vf[2][4];
    // tile t0 (K in Ks[0])
    read_vf(vf);
    __syncthreads();                     // all waves done reading V(t0)
    STAGE_V((t0 + 1) * 64);
    STAGE_K(1, (t0 + 1) * 64);
    compute_tile(Ks[0], vf);
    __syncthreads();                     // drains vmcnt: V(t0+1)/K(t0+1) landed
    // tile t0+1 (K in Ks[1])
    read_vf(vf);
    __syncthreads();                     // all waves done reading V(t0+1)
    if (it < 15) {
      STAGE_V((t0 + 2) * 64);
      STAGE_K(0, (t0 + 2) * 64);
    }
    compute_tile(Ks[1], vf);
    __syncthreads();                     // drains vmcnt: next tile landed
  }
#undef STAGE_K
#undef STAGE_V

  // l lives per-lane for q = ll; finish reduction over lg, then fetch per-row.
  float l1 = l1p; l1 += __shfl_xor(l1, 16); l1 += __shfl_xor(l1, 32);
  float l2 = l2p; l2 += __shfl_xor(l2, 16); l2 += __shfl_xor(l2, 32);
  float i1[4], i2[4];
#pragma unroll
  for (int j = 0; j < 4; ++j) {
    int src = (lane & 48) | ((lg << 2) + j);   // lane with ll == q-row
    i1[j] = 1.f / __shfl(l1, src);
    i2[j] = 1.f / __shfl(l2, src);
  }

  float ss[4] = {0.f, 0.f, 0.f, 0.f};
  f32x4 ov[4];
#pragma unroll
  for (int nb = 0; nb < 4; ++nb) {
#pragma unroll
    for (int j = 0; j < 4; ++j) {
      float x = o1[nb][j] * i1[j] - lam * (o2[nb][j] * i2[j]);
      ov[nb][j] = x;
      ss[j] += x * x;
    }
  }
#pragma unroll
  for (int mask = 1; mask < 16; mask <<= 1)
#pragma unroll
    for (int j = 0; j < 4; ++j) ss[j] += __shfl_xor(ss[j], mask);
  float nf[4];
#pragma unroll
  for (int j = 0; j < 4; ++j) nf[j] = rsqrtf(ss[j] * (1.f / 64.f) + 1e-5f);
  const size_t orow0 = (size_t)(b * 2048 + qt * 64 + wave * 16);
#pragma unroll
  for (int nb = 0; nb < 4; ++nb) {
    int d = nb * 16 + ll;
    float sw = subln[d] * ONE_MINUS_LI;
#pragma unroll
    for (int j = 0; j < 4; ++j) {
      int r = (lg << 2) + j;
      o[(orow0 + r) * 1024 + (h << 6) + d] = f2bf(ov[nb][j] * nf[j] * sw);
    }
  }
}

extern "C" void kernel_launch(void* const* d_in, const int* in_sizes, int n_in,
                              void* d_out, int out_size, void* d_ws, size_t ws_size,
                              hipStream_t stream) {
  const float* x      = (const float*)d_in[0];
  const float* W_qkv  = (const float*)d_in[1];
  const float* W_proj = (const float*)d_in[2];
  const float* b_proj = (const float*)d_in[3];
  const float* lq1    = (const float*)d_in[4];
  const float* lk1    = (const float*)d_in[5];
  const float* lq2    = (const float*)d_in[6];
  const float* lk2    = (const float*)d_in[7];
  const float* subln  = (const float*)d_in[8];

  char* ws = (char*)d_ws;
  ushort_t* xb     = (ushort_t*)(ws);                 //  8,388,608 B (4096x1024 bf16)
  ushort_t* qkb    = (ushort_t*)(ws + 8388608);       // 16,777,216 B (4096x2048 bf16, q|k)
  ushort_t* vtb    = (ushort_t*)(ws + 25165824);      //  8,388,608 B (V^T: [2*16*64][2048])
  ushort_t* wqkvT  = (ushort_t*)(ws + 33554432);      //  6,291,456 B (3072x1024 bf16)
  ushort_t* wprojT = (ushort_t*)(ws + 39845888);      //  2,097,152 B (1024x1024 bf16)
  ushort_t* ob     = (ushort_t*)(ws + 41943040);      //  8,388,608 B (4096x1024 bf16)

  cvt_f32_bf16<<<2048, 256, 0, stream>>>(x, xb, 4096 * 1024);
  transpose_to_bf16<<<dim3(96, 32), 256, 0, stream>>>(W_qkv, wqkvT, 1024, 3072);
  transpose_to_bf16<<<dim3(32, 32), 256, 0, stream>>>(W_proj, wprojT, 1024, 1024);
  gemm_bt<1><<<dim3(32, 24), 256, 0, stream>>>(xb, wqkvT, (void*)qkb, vtb, nullptr, 4096, 3072, 1024);
  diff_attn<<<dim3(32, 16, 2), 256, 0, stream>>>(qkb, vtb, ob, lq1, lk1, lq2, lk2, subln);
  gemm_bt<0><<<dim3(32, 8), 256, 0, stream>>>(ob, wprojT, d_out, nullptr, b_proj, 4096, 1024, 1024);
}

// Round 13
// 172.292 us; speedup vs baseline: 1.0044x; 1.0044x over previous
//
#include <hip/hip_runtime.h>

typedef unsigned short ushort_t;
typedef unsigned int uint_t;
typedef __attribute__((ext_vector_type(4))) float f32x4;
typedef __attribute__((ext_vector_type(8))) __bf16 bf16x8;

#define LAMBDA_INIT 0.7836057665316245f
#define ONE_MINUS_LI 0.21639423346837552f
#define QSCALE_LOG2E 0.25505654442552663f  // 32^-0.5 * log2(e)

__device__ inline ushort_t f2bf(float f) {
  union { float f; unsigned u; } v; v.f = f;
  unsigned r = (v.u + 0x7FFFu + ((v.u >> 16) & 1u)) >> 16;
  return (ushort_t)r;
}

// bare v_exp_f32 (args bounded, no libm range fixup needed)
__device__ inline float fexp2(float x) {
  float r;
  asm("v_exp_f32 %0, %1" : "=v"(r) : "v"(x));
  return r;
}

// pack 2 f32 -> 2 bf16 (RNE), lo in low half
__device__ inline uint_t cvtpk(float lo, float hi) {
  uint_t r;
  asm("v_cvt_pk_bf16_f32 %0, %1, %2" : "=v"(r) : "v"(lo), "v"(hi));
  return r;
}

__device__ inline f32x4 zero4() { f32x4 z = {0.f, 0.f, 0.f, 0.f}; return z; }

__device__ inline f32x4 mfma16(bf16x8 a, bf16x8 b, f32x4 c) {
  return __builtin_amdgcn_mfma_f32_16x16x32_bf16(a, b, c, 0, 0, 0);
}

__device__ inline void gload_lds16(const void* g, void* l) {
  __builtin_amdgcn_global_load_lds(
      (const __attribute__((address_space(1))) unsigned int*)g,
      (__attribute__((address_space(3))) unsigned int*)l, 16, 0, 0);
}

// ---------------- convert x (fp32 -> bf16) ----------------
__global__ __launch_bounds__(256) void cvt_f32_bf16(const float* __restrict__ in,
                                                    ushort_t* __restrict__ out, int n) {
  int i = (blockIdx.x * 256 + threadIdx.x) * 8;
  if (i >= n) return;
  float4 a = *(const float4*)(in + i);
  float4 b = *(const float4*)(in + i + 4);
  uint4 pack;
  pack.x = cvtpk(a.x, a.y);
  pack.y = cvtpk(a.z, a.w);
  pack.z = cvtpk(b.x, b.y);
  pack.w = cvtpk(b.z, b.w);
  *(uint4*)(out + i) = pack;
}

// ---------------- transpose W (KxN fp32) -> WT (NxK bf16) ----------------
__global__ __launch_bounds__(256) void transpose_to_bf16(const float* __restrict__ W,
                                                         ushort_t* __restrict__ WT,
                                                         int K, int N) {
  __shared__ float tile[32][33];
  int n0 = blockIdx.x * 32, k0 = blockIdx.y * 32;
  int tx = threadIdx.x & 31, ty = threadIdx.x >> 5;
#pragma unroll
  for (int j = 0; j < 4; ++j) {
    int k = k0 + ty + j * 8;
    tile[ty + j * 8][tx] = W[(size_t)k * N + n0 + tx];
  }
  __syncthreads();
#pragma unroll
  for (int j = 0; j < 4; ++j) {
    int n = n0 + ty + j * 8;
    WT[(size_t)n * K + k0 + tx] = f2bf(tile[tx][ty + j * 8]);
  }
}

// ---------------- GEMM: C[M,N] = A[M,K] * Bt[N,K]^T, bf16 in ----------------
// XCD-aware block swizzle: XCD r hosts contiguous col-panels -> B reuse in L2.
template <int MODE>
__global__ __launch_bounds__(256) void gemm_bt(const ushort_t* __restrict__ A,
                                               const ushort_t* __restrict__ Bt,
                                               void* __restrict__ C,
                                               ushort_t* __restrict__ vt_out,
                                               const float* __restrict__ bias,
                                               int M, int N, int K) {
  __shared__ ushort_t As[128 * 32];
  __shared__ ushort_t Bs[128 * 32];
  const int tid = threadIdx.x;
  const int wave = tid >> 6, lane = tid & 63;
  const int wr = wave >> 1, wc = wave & 1;
  const int lg = lane >> 4, ll = lane & 15;

  // XCD swizzle (nwg divisible by 8: 768 and 256)
  const int lin = blockIdx.x + gridDim.x * blockIdx.y;
  const int cpx = (gridDim.x * gridDim.y) >> 3;
  const int swz = (lin & 7) * cpx + (lin >> 3);
  const int row0 = (swz % gridDim.x) * 128, col0 = (swz / gridDim.x) * 128;

  f32x4 acc[4][4];
#pragma unroll
  for (int m = 0; m < 4; ++m)
#pragma unroll
    for (int n = 0; n < 4; ++n) acc[m][n] = zero4();

  for (int k0 = 0; k0 < K; k0 += 32) {
    __syncthreads();
#pragma unroll
    for (int i = 0; i < 2; ++i) {
      int c = tid + i * 256;
      int r = c >> 2, ko = (c & 3) << 3;
      gload_lds16(A + (size_t)(row0 + r) * K + k0 + ko,
                  (char*)As + (size_t)(wave * 64 + i * 256) * 16);
      gload_lds16(Bt + (size_t)(col0 + r) * K + k0 + ko,
                  (char*)Bs + (size_t)(wave * 64 + i * 256) * 16);
    }
    __syncthreads();
    bf16x8 af[4], bf[4];
#pragma unroll
    for (int m = 0; m < 4; ++m)
      af[m] = *(const bf16x8*)(As + (wr * 64 + m * 16 + ll) * 32 + (lg << 3));
#pragma unroll
    for (int n = 0; n < 4; ++n)
      bf[n] = *(const bf16x8*)(Bs + (wc * 64 + n * 16 + ll) * 32 + (lg << 3));
#pragma unroll
    for (int m = 0; m < 4; ++m)
#pragma unroll
      for (int n = 0; n < 4; ++n) acc[m][n] = mfma16(af[m], bf[n], acc[m][n]);
  }

#pragma unroll
  for (int m = 0; m < 4; ++m) {
#pragma unroll
    for (int n = 0; n < 4; ++n) {
      int gc = col0 + wc * 64 + n * 16 + ll;
      int gr0 = row0 + wr * 64 + m * 16 + (lg << 2);
      if (MODE == 0) {
#pragma unroll
        for (int j = 0; j < 4; ++j)
          ((float*)C)[(size_t)(gr0 + j) * N + gc] = acc[m][n][j] + bias[gc];
      } else {
        if (gc < 2048) {
          float sc = (gc < 1024) ? QSCALE_LOG2E : 1.0f;
#pragma unroll
          for (int j = 0; j < 4; ++j)
            ((ushort_t*)C)[(size_t)(gr0 + j) * 2048 + gc] = f2bf(acc[m][n][j] * sc);
        } else {
          // V columns -> transposed store, 4 consecutive n packed into 8B
          int hv = (gc - 2048) >> 6, dv = (gc - 2048) & 63;
          int bb = gr0 >> 11, nn = gr0 & 2047;
          uint2 w;
          w.x = cvtpk(acc[m][n][0], acc[m][n][1]);
          w.y = cvtpk(acc[m][n][2], acc[m][n][3]);
          *(uint2*)(vt_out + ((size_t)((bb * 16 + hv) * 64 + dv)) * 2048 + nn) = w;
        }
      }
    }
  }
}

// ---------------- differential flash attention (swapped-QK, static max, dbuf) ----------------
// R11 kernel (proven 97us) with ONE change: per-pass P buffers. The two
// attention maps are independent until the epilogue, but sharing one P region
// forced the compiler to serialize pass0's P-reads before pass1's P-writes.
// Split P -> the two QK/exp/PV chains overlap (2x MFMA ILP). LDS 51200 B,
// still 3 blocks/CU (residency unchanged; pure ILP delta).
// + T5 setprio(1) around MFMA clusters.
__global__ __launch_bounds__(256) void diff_attn(const ushort_t* __restrict__ qk,
                                                 const ushort_t* __restrict__ vt,
                                                 ushort_t* __restrict__ o,
                                                 const float* __restrict__ lq1,
                                                 const float* __restrict__ lk1,
                                                 const float* __restrict__ lq2,
                                                 const float* __restrict__ lk2,
                                                 const float* __restrict__ subln) {
  const int lin = blockIdx.x + (blockIdx.y << 5) + (blockIdx.z << 9);
  const int swz = ((lin & 7) << 7) + (lin >> 3);    // XCD r -> swz in [128r, 128r+128)
  const int qt = swz & 31, h = (swz >> 5) & 15, b = swz >> 9;
  const int tid = threadIdx.x, wave = tid >> 6, lane = tid & 63;
  const int lg = lane >> 4, ll = lane & 15;

  const size_t qbase = (size_t)b * 2048 * 2048;
  const int cq1 = (h << 5), cq2 = 512 + (h << 5);
  const int ck1 = 1024 + (h << 5), ck2 = 1536 + (h << 5);
  const size_t vbase = (size_t)((b * 16 + h) * 64) * 2048;

  float sl1 = 0.f, sl2 = 0.f;
  for (int j = 0; j < 32; ++j) { sl1 += lq1[j] * lk1[j]; sl2 += lq2[j] * lk2[j]; }
  const float lam = __expf(sl1) - __expf(sl2) + LAMBDA_INIT;

  __shared__ ushort_t Ks[2][64 * 64];     // [kv r][8 chunks: 0-3 K1, 4-7 K2], XOR-8 swizzled
  __shared__ ushort_t Vs[2][64 * 64];     // [d r][8 t-chunks], XOR-8 swizzled
  __shared__ ushort_t Pl[4][2][16 * 72];  // per-wave, PER-PASS P (stride 72, proven affine)

  // Q fragments (B-operand of swapped QK^T)
  const int qrow = qt * 64 + wave * 16 + ll;
  const bf16x8 q1f = *(const bf16x8*)(qk + qbase + (size_t)qrow * 2048 + cq1 + (lg << 3));
  const bf16x8 q2f = *(const bf16x8*)(qk + qbase + (size_t)qrow * 2048 + cq2 + (lg << 3));

  f32x4 o1[4], o2[4];
#pragma unroll
  for (int nb = 0; nb < 4; ++nb) { o1[nb] = zero4(); o2[nb] = zero4(); }
  float l1p = 0.f, l2p = 0.f;
  ushort_t* Pw0 = &Pl[wave][0][0];
  ushort_t* Pw1 = &Pl[wave][1][0];

  // staging geometry: slot s -> row r = s>>3, lds chunk s&7 holds global chunk (s&7)^(r&7)
  const int s0 = tid, s1 = tid + 256;
  const int r0 = s0 >> 3, c0 = (s0 & 7) ^ (r0 & 7);
  const int r1 = s1 >> 3, c1 = (s1 & 7) ^ (r1 & 7);
  const int kc0 = ((c0 & 4) ? ck2 : ck1) + ((c0 & 3) << 3);
  const int kc1 = ((c1 & 4) ? ck2 : ck1) + ((c1 & 3) << 3);
  const int ub0 = (wave << 6) * 16;
  const int ub1 = ((wave << 6) + 256) * 16;

#define STAGE(buf, kv0)                                                                   \
  do {                                                                                    \
    gload_lds16(qk + qbase + (size_t)((kv0) + r0) * 2048 + kc0, (char*)Ks[buf] + ub0);    \
    gload_lds16(qk + qbase + (size_t)((kv0) + r1) * 2048 + kc1, (char*)Ks[buf] + ub1);    \
    gload_lds16(vt + vbase + (size_t)r0 * 2048 + (kv0) + (c0 << 3), (char*)Vs[buf] + ub0);\
    gload_lds16(vt + vbase + (size_t)r1 * 2048 + (kv0) + (c1 << 3), (char*)Vs[buf] + ub1);\
  } while (0)

  auto compute_tile = [&](const ushort_t* Kc, const ushort_t* Vc) {
    bf16x8 vf[2][4];
#pragma unroll
    for (int ks = 0; ks < 2; ++ks)
#pragma unroll
      for (int nb = 0; nb < 4; ++nb)
        vf[ks][nb] = *(const bf16x8*)(Vc + nb * 1024 + ll * 64 + (((ks * 4 + lg) ^ (ll & 7)) << 3));
#pragma unroll
    for (int pass = 0; pass < 2; ++pass) {
      const int cK = (lg ^ (ll & 7)) ^ (pass << 2);
      ushort_t* Pw = pass ? Pw1 : Pw0;
      bf16x8 kf[4];
#pragma unroll
      for (int nb = 0; nb < 4; ++nb)
        kf[nb] = *(const bf16x8*)(Kc + nb * 1024 + ll * 64 + (cK << 3));
      const bf16x8 qf = pass ? q2f : q1f;
      f32x4* oacc = pass ? o2 : o1;
      f32x4 s[4];
      __builtin_amdgcn_s_setprio(1);
#pragma unroll
      for (int nb = 0; nb < 4; ++nb)
        s[nb] = mfma16(kf[nb], qf, zero4());   // D: row=k (4lg+i), col=q (ll)
      __builtin_amdgcn_s_setprio(0);
      float part = 0.f;
#pragma unroll
      for (int nb = 0; nb < 4; ++nb) {
        float e0 = fexp2(s[nb][0]), e1 = fexp2(s[nb][1]);
        float e2 = fexp2(s[nb][2]), e3 = fexp2(s[nb][3]);
        part += (e0 + e1) + (e2 + e3);
        uint2 w;
        w.x = cvtpk(e0, e1);
        w.y = cvtpk(e2, e3);
        // P[q=ll][k = nb*16 + 4lg .. +3]
        *(uint2*)(Pw + ll * 72 + nb * 16 + (lg << 2)) = w;
      }
      if (pass) l2p += part; else l1p += part;
      __builtin_amdgcn_s_setprio(1);
#pragma unroll
      for (int ks = 0; ks < 2; ++ks) {
        bf16x8 pf = *(const bf16x8*)(Pw + ll * 72 + ks * 32 + (lg << 3));
#pragma unroll
        for (int nb = 0; nb < 4; ++nb) oacc[nb] = mfma16(pf, vf[ks][nb], oacc[nb]);
      }
      __builtin_amdgcn_s_setprio(0);
    }
  };

  STAGE(0, 0);
  __syncthreads();
  for (int tt = 0; tt < 16; ++tt) {
    STAGE(1, (tt * 2 + 1) * 64);
    compute_tile(Ks[0], Vs[0]);
    __syncthreads();
    if (tt < 15) STAGE(0, (tt * 2 + 2) * 64);
    compute_tile(Ks[1], Vs[1]);
    __syncthreads();
  }
#undef STAGE

  // l lives per-lane for q = ll; finish reduction over lg, then fetch per-row.
  float l1 = l1p; l1 += __shfl_xor(l1, 16); l1 += __shfl_xor(l1, 32);
  float l2 = l2p; l2 += __shfl_xor(l2, 16); l2 += __shfl_xor(l2, 32);
  float i1[4], i2[4];
#pragma unroll
  for (int j = 0; j < 4; ++j) {
    int src = (lane & 48) | ((lg << 2) + j);   // lane with ll == q-row
    i1[j] = 1.f / __shfl(l1, src);
    i2[j] = 1.f / __shfl(l2, src);
  }

  float ss[4] = {0.f, 0.f, 0.f, 0.f};
  f32x4 ov[4];
#pragma unroll
  for (int nb = 0; nb < 4; ++nb) {
#pragma unroll
    for (int j = 0; j < 4; ++j) {
      float x = o1[nb][j] * i1[j] - lam * (o2[nb][j] * i2[j]);
      ov[nb][j] = x;
      ss[j] += x * x;
    }
  }
#pragma unroll
  for (int mask = 1; mask < 16; mask <<= 1)
#pragma unroll
    for (int j = 0; j < 4; ++j) ss[j] += __shfl_xor(ss[j], mask);
  float nf[4];
#pragma unroll
  for (int j = 0; j < 4; ++j) nf[j] = rsqrtf(ss[j] * (1.f / 64.f) + 1e-5f);
  const size_t orow0 = (size_t)(b * 2048 + qt * 64 + wave * 16);
#pragma unroll
  for (int nb = 0; nb < 4; ++nb) {
    int d = nb * 16 + ll;
    float sw = subln[d] * ONE_MINUS_LI;
#pragma unroll
    for (int j = 0; j < 4; ++j) {
      int r = (lg << 2) + j;
      o[(orow0 + r) * 1024 + (h << 6) + d] = f2bf(ov[nb][j] * nf[j] * sw);
    }
  }
}

extern "C" void kernel_launch(void* const* d_in, const int* in_sizes, int n_in,
                              void* d_out, int out_size, void* d_ws, size_t ws_size,
                              hipStream_t stream) {
  const float* x      = (const float*)d_in[0];
  const float* W_qkv  = (const float*)d_in[1];
  const float* W_proj = (const float*)d_in[2];
  const float* b_proj = (const float*)d_in[3];
  const float* lq1    = (const float*)d_in[4];
  const float* lk1    = (const float*)d_in[5];
  const float* lq2    = (const float*)d_in[6];
  const float* lk2    = (const float*)d_in[7];
  const float* subln  = (const float*)d_in[8];

  char* ws = (char*)d_ws;
  ushort_t* xb     = (ushort_t*)(ws);                 //  8,388,608 B (4096x1024 bf16)
  ushort_t* qkb    = (ushort_t*)(ws + 8388608);       // 16,777,216 B (4096x2048 bf16, q|k)
  ushort_t* vtb    = (ushort_t*)(ws + 25165824);      //  8,388,608 B (V^T: [2*16*64][2048])
  ushort_t* wqkvT  = (ushort_t*)(ws + 33554432);      //  6,291,456 B (3072x1024 bf16)
  ushort_t* wprojT = (ushort_t*)(ws + 39845888);      //  2,097,152 B (1024x1024 bf16)
  ushort_t* ob     = (ushort_t*)(ws + 41943040);      //  8,388,608 B (4096x1024 bf16)

  cvt_f32_bf16<<<2048, 256, 0, stream>>>(x, xb, 4096 * 1024);
  transpose_to_bf16<<<dim3(96, 32), 256, 0, stream>>>(W_qkv, wqkvT, 1024, 3072);
  transpose_to_bf16<<<dim3(32, 32), 256, 0, stream>>>(W_proj, wprojT, 1024, 1024);
  gemm_bt<1><<<dim3(32, 24), 256, 0, stream>>>(xb, wqkvT, (void*)qkb, vtb, nullptr, 4096, 3072, 1024);
  diff_attn<<<dim3(32, 16, 2), 256, 0, stream>>>(qkb, vtb, ob, lq1, lk1, lq2, lk2, subln);
  gemm_bt<0><<<dim3(32, 8), 256, 0, stream>>>(ob, wprojT, d_out, nullptr, b_proj, 4096, 1024, 1024);
}

// Round 14
// 170.450 us; speedup vs baseline: 1.0152x; 1.0108x over previous
//
#include <hip/hip_runtime.h>

typedef unsigned short ushort_t;
typedef unsigned int uint_t;
typedef __attribute__((ext_vector_type(4))) float f32x4;
typedef __attribute__((ext_vector_type(8))) __bf16 bf16x8;

#define LAMBDA_INIT 0.7836057665316245f
#define ONE_MINUS_LI 0.21639423346837552f
#define QSCALE_LOG2E 0.25505654442552663f  // 32^-0.5 * log2(e)

__device__ inline ushort_t f2bf(float f) {
  union { float f; unsigned u; } v; v.f = f;
  unsigned r = (v.u + 0x7FFFu + ((v.u >> 16) & 1u)) >> 16;
  return (ushort_t)r;
}

// bare v_exp_f32 (args bounded, no libm range fixup needed)
__device__ inline float fexp2(float x) {
  float r;
  asm("v_exp_f32 %0, %1" : "=v"(r) : "v"(x));
  return r;
}

// pack 2 f32 -> 2 bf16 (RNE), lo in low half
__device__ inline uint_t cvtpk(float lo, float hi) {
  uint_t r;
  asm("v_cvt_pk_bf16_f32 %0, %1, %2" : "=v"(r) : "v"(lo), "v"(hi));
  return r;
}

__device__ inline f32x4 zero4() { f32x4 z = {0.f, 0.f, 0.f, 0.f}; return z; }

__device__ inline f32x4 mfma16(bf16x8 a, bf16x8 b, f32x4 c) {
  return __builtin_amdgcn_mfma_f32_16x16x32_bf16(a, b, c, 0, 0, 0);
}

__device__ inline void gload_lds16(const void* g, void* l) {
  __builtin_amdgcn_global_load_lds(
      (const __attribute__((address_space(1))) unsigned int*)g,
      (__attribute__((address_space(3))) unsigned int*)l, 16, 0, 0);
}

// ---------------- convert x (fp32 -> bf16) ----------------
__global__ __launch_bounds__(256) void cvt_f32_bf16(const float* __restrict__ in,
                                                    ushort_t* __restrict__ out, int n) {
  int i = (blockIdx.x * 256 + threadIdx.x) * 8;
  if (i >= n) return;
  float4 a = *(const float4*)(in + i);
  float4 b = *(const float4*)(in + i + 4);
  uint4 pack;
  pack.x = cvtpk(a.x, a.y);
  pack.y = cvtpk(a.z, a.w);
  pack.z = cvtpk(b.x, b.y);
  pack.w = cvtpk(b.z, b.w);
  *(uint4*)(out + i) = pack;
}

// ---------------- transpose W (KxN fp32) -> WT (NxK bf16) ----------------
__global__ __launch_bounds__(256) void transpose_to_bf16(const float* __restrict__ W,
                                                         ushort_t* __restrict__ WT,
                                                         int K, int N) {
  __shared__ float tile[32][33];
  int n0 = blockIdx.x * 32, k0 = blockIdx.y * 32;
  int tx = threadIdx.x & 31, ty = threadIdx.x >> 5;
#pragma unroll
  for (int j = 0; j < 4; ++j) {
    int k = k0 + ty + j * 8;
    tile[ty + j * 8][tx] = W[(size_t)k * N + n0 + tx];
  }
  __syncthreads();
#pragma unroll
  for (int j = 0; j < 4; ++j) {
    int n = n0 + ty + j * 8;
    WT[(size_t)n * K + k0 + tx] = f2bf(tile[tx][ty + j * 8]);
  }
}

// ---------------- GEMM: C[M,N] = A[M,K] * Bt[N,K]^T, bf16 in ----------------
// XCD-aware block swizzle: XCD r hosts contiguous col-panels -> B reuse in L2.
template <int MODE>
__global__ __launch_bounds__(256) void gemm_bt(const ushort_t* __restrict__ A,
                                               const ushort_t* __restrict__ Bt,
                                               void* __restrict__ C,
                                               ushort_t* __restrict__ vt_out,
                                               const float* __restrict__ bias,
                                               int M, int N, int K) {
  __shared__ ushort_t As[128 * 32];
  __shared__ ushort_t Bs[128 * 32];
  const int tid = threadIdx.x;
  const int wave = tid >> 6, lane = tid & 63;
  const int wr = wave >> 1, wc = wave & 1;
  const int lg = lane >> 4, ll = lane & 15;

  // XCD swizzle (nwg divisible by 8: 768 and 256)
  const int lin = blockIdx.x + gridDim.x * blockIdx.y;
  const int cpx = (gridDim.x * gridDim.y) >> 3;
  const int swz = (lin & 7) * cpx + (lin >> 3);
  const int row0 = (swz % gridDim.x) * 128, col0 = (swz / gridDim.x) * 128;

  f32x4 acc[4][4];
#pragma unroll
  for (int m = 0; m < 4; ++m)
#pragma unroll
    for (int n = 0; n < 4; ++n) acc[m][n] = zero4();

  for (int k0 = 0; k0 < K; k0 += 32) {
    __syncthreads();
#pragma unroll
    for (int i = 0; i < 2; ++i) {
      int c = tid + i * 256;
      int r = c >> 2, ko = (c & 3) << 3;
      gload_lds16(A + (size_t)(row0 + r) * K + k0 + ko,
                  (char*)As + (size_t)(wave * 64 + i * 256) * 16);
      gload_lds16(Bt + (size_t)(col0 + r) * K + k0 + ko,
                  (char*)Bs + (size_t)(wave * 64 + i * 256) * 16);
    }
    __syncthreads();
    bf16x8 af[4], bf[4];
#pragma unroll
    for (int m = 0; m < 4; ++m)
      af[m] = *(const bf16x8*)(As + (wr * 64 + m * 16 + ll) * 32 + (lg << 3));
#pragma unroll
    for (int n = 0; n < 4; ++n)
      bf[n] = *(const bf16x8*)(Bs + (wc * 64 + n * 16 + ll) * 32 + (lg << 3));
#pragma unroll
    for (int m = 0; m < 4; ++m)
#pragma unroll
      for (int n = 0; n < 4; ++n) acc[m][n] = mfma16(af[m], bf[n], acc[m][n]);
  }

#pragma unroll
  for (int m = 0; m < 4; ++m) {
#pragma unroll
    for (int n = 0; n < 4; ++n) {
      int gc = col0 + wc * 64 + n * 16 + ll;
      int gr0 = row0 + wr * 64 + m * 16 + (lg << 2);
      if (MODE == 0) {
#pragma unroll
        for (int j = 0; j < 4; ++j)
          ((float*)C)[(size_t)(gr0 + j) * N + gc] = acc[m][n][j] + bias[gc];
      } else {
        if (gc < 2048) {
          float sc = (gc < 1024) ? QSCALE_LOG2E : 1.0f;
#pragma unroll
          for (int j = 0; j < 4; ++j)
            ((ushort_t*)C)[(size_t)(gr0 + j) * 2048 + gc] = f2bf(acc[m][n][j] * sc);
        } else {
          // V columns -> transposed store, 4 consecutive n packed into 8B
          int hv = (gc - 2048) >> 6, dv = (gc - 2048) & 63;
          int bb = gr0 >> 11, nn = gr0 & 2047;
          uint2 w;
          w.x = cvtpk(acc[m][n][0], acc[m][n][1]);
          w.y = cvtpk(acc[m][n][2], acc[m][n][3]);
          *(uint2*)(vt_out + ((size_t)((bb * 16 + hv) * 64 + dv)) * 2048 + nn) = w;
        }
      }
    }
  }
}

// ---------------- differential flash attention (QBLK=128, 8 waves, swapped-QK) ----------------
// Per-wave code is byte-identical to the proven R11/R13 kernel (each wave does
// BOTH passes for its own 16 q-rows; no cross-wave merge). 512-thread blocks:
// 8 waves share each staged K/V tile (staging per unit work halves), grid 512
// = exactly 2 blocks/CU resident (LDS 68KB) -> 16 waves/CU vs 12, zero tail.
__global__ __launch_bounds__(512) void diff_attn(const ushort_t* __restrict__ qk,
                                                 const ushort_t* __restrict__ vt,
                                                 ushort_t* __restrict__ o,
                                                 const float* __restrict__ lq1,
                                                 const float* __restrict__ lk1,
                                                 const float* __restrict__ lq2,
                                                 const float* __restrict__ lk2,
                                                 const float* __restrict__ subln) {
  const int lin = blockIdx.x + (blockIdx.y << 4) + (blockIdx.z << 8);
  const int swz = ((lin & 7) << 6) + (lin >> 3);    // XCD r -> swz in [64r, 64r+64)
  const int qt = swz & 15, h = (swz >> 4) & 15, b = swz >> 8;
  const int tid = threadIdx.x, wave = tid >> 6, lane = tid & 63;
  const int lg = lane >> 4, ll = lane & 15;

  const size_t qbase = (size_t)b * 2048 * 2048;
  const int cq1 = (h << 5), cq2 = 512 + (h << 5);
  const int ck1 = 1024 + (h << 5), ck2 = 1536 + (h << 5);
  const size_t vbase = (size_t)((b * 16 + h) * 64) * 2048;

  float sl1 = 0.f, sl2 = 0.f;
  for (int j = 0; j < 32; ++j) { sl1 += lq1[j] * lk1[j]; sl2 += lq2[j] * lk2[j]; }
  const float lam = __expf(sl1) - __expf(sl2) + LAMBDA_INIT;

  __shared__ ushort_t Ks[2][64 * 64];     // [kv r][8 chunks: 0-3 K1, 4-7 K2], XOR-8 swizzled
  __shared__ ushort_t Vs[2][64 * 64];     // [d r][8 t-chunks], XOR-8 swizzled
  __shared__ ushort_t Pl[8][2][16 * 72];  // per-wave, per-pass P (stride 72, proven affine)

  // Q fragments (B-operand of swapped QK^T); this wave owns q-rows qt*128+wave*16..+15
  const int qrow = qt * 128 + wave * 16 + ll;
  const bf16x8 q1f = *(const bf16x8*)(qk + qbase + (size_t)qrow * 2048 + cq1 + (lg << 3));
  const bf16x8 q2f = *(const bf16x8*)(qk + qbase + (size_t)qrow * 2048 + cq2 + (lg << 3));

  f32x4 o1[4], o2[4];
#pragma unroll
  for (int nb = 0; nb < 4; ++nb) { o1[nb] = zero4(); o2[nb] = zero4(); }
  float l1p = 0.f, l2p = 0.f;
  ushort_t* Pw0 = &Pl[wave][0][0];
  ushort_t* Pw1 = &Pl[wave][1][0];

  // staging: 512 threads, ONE 16B K-slot + ONE 16B V-slot each.
  // slot s=tid -> row r = s>>3, lds chunk s&7 holds global chunk (s&7)^(r&7)
  const int r0 = tid >> 3, c0 = (tid & 7) ^ (r0 & 7);
  const int kc0 = ((c0 & 4) ? ck2 : ck1) + ((c0 & 3) << 3);
  const int ub0 = tid << 4;   // wave-contiguous: base wave*1024 + lane*16

#define STAGE(buf, kv0)                                                                   \
  do {                                                                                    \
    gload_lds16(qk + qbase + (size_t)((kv0) + r0) * 2048 + kc0, (char*)Ks[buf] + ub0);    \
    gload_lds16(vt + vbase + (size_t)r0 * 2048 + (kv0) + (c0 << 3), (char*)Vs[buf] + ub0);\
  } while (0)

  auto compute_tile = [&](const ushort_t* Kc, const ushort_t* Vc) {
    bf16x8 vf[2][4];
#pragma unroll
    for (int ks = 0; ks < 2; ++ks)
#pragma unroll
      for (int nb = 0; nb < 4; ++nb)
        vf[ks][nb] = *(const bf16x8*)(Vc + nb * 1024 + ll * 64 + (((ks * 4 + lg) ^ (ll & 7)) << 3));
#pragma unroll
    for (int pass = 0; pass < 2; ++pass) {
      const int cK = (lg ^ (ll & 7)) ^ (pass << 2);
      ushort_t* Pw = pass ? Pw1 : Pw0;
      bf16x8 kf[4];
#pragma unroll
      for (int nb = 0; nb < 4; ++nb)
        kf[nb] = *(const bf16x8*)(Kc + nb * 1024 + ll * 64 + (cK << 3));
      const bf16x8 qf = pass ? q2f : q1f;
      f32x4* oacc = pass ? o2 : o1;
      f32x4 s[4];
      __builtin_amdgcn_s_setprio(1);
#pragma unroll
      for (int nb = 0; nb < 4; ++nb)
        s[nb] = mfma16(kf[nb], qf, zero4());   // D: row=k (4lg+i), col=q (ll)
      __builtin_amdgcn_s_setprio(0);
      float part = 0.f;
#pragma unroll
      for (int nb = 0; nb < 4; ++nb) {
        float e0 = fexp2(s[nb][0]), e1 = fexp2(s[nb][1]);
        float e2 = fexp2(s[nb][2]), e3 = fexp2(s[nb][3]);
        part += (e0 + e1) + (e2 + e3);
        uint2 w;
        w.x = cvtpk(e0, e1);
        w.y = cvtpk(e2, e3);
        // P[q=ll][k = nb*16 + 4lg .. +3]
        *(uint2*)(Pw + ll * 72 + nb * 16 + (lg << 2)) = w;
      }
      if (pass) l2p += part; else l1p += part;
      __builtin_amdgcn_s_setprio(1);
#pragma unroll
      for (int ks = 0; ks < 2; ++ks) {
        bf16x8 pf = *(const bf16x8*)(Pw + ll * 72 + ks * 32 + (lg << 3));
#pragma unroll
        for (int nb = 0; nb < 4; ++nb) oacc[nb] = mfma16(pf, vf[ks][nb], oacc[nb]);
      }
      __builtin_amdgcn_s_setprio(0);
    }
  };

  STAGE(0, 0);
  __syncthreads();
  for (int tt = 0; tt < 16; ++tt) {
    STAGE(1, (tt * 2 + 1) * 64);
    compute_tile(Ks[0], Vs[0]);
    __syncthreads();
    if (tt < 15) STAGE(0, (tt * 2 + 2) * 64);
    compute_tile(Ks[1], Vs[1]);
    __syncthreads();
  }
#undef STAGE

  // l lives per-lane for q = ll; finish reduction over lg, then fetch per-row.
  float l1 = l1p; l1 += __shfl_xor(l1, 16); l1 += __shfl_xor(l1, 32);
  float l2 = l2p; l2 += __shfl_xor(l2, 16); l2 += __shfl_xor(l2, 32);
  float i1[4], i2[4];
#pragma unroll
  for (int j = 0; j < 4; ++j) {
    int src = (lane & 48) | ((lg << 2) + j);   // lane with ll == q-row
    i1[j] = 1.f / __shfl(l1, src);
    i2[j] = 1.f / __shfl(l2, src);
  }

  float ss[4] = {0.f, 0.f, 0.f, 0.f};
  f32x4 ov[4];
#pragma unroll
  for (int nb = 0; nb < 4; ++nb) {
#pragma unroll
    for (int j = 0; j < 4; ++j) {
      float x = o1[nb][j] * i1[j] - lam * (o2[nb][j] * i2[j]);
      ov[nb][j] = x;
      ss[j] += x * x;
    }
  }
#pragma unroll
  for (int mask = 1; mask < 16; mask <<= 1)
#pragma unroll
    for (int j = 0; j < 4; ++j) ss[j] += __shfl_xor(ss[j], mask);
  float nf[4];
#pragma unroll
  for (int j = 0; j < 4; ++j) nf[j] = rsqrtf(ss[j] * (1.f / 64.f) + 1e-5f);
  const size_t orow0 = (size_t)(b * 2048 + qt * 128 + wave * 16);
#pragma unroll
  for (int nb = 0; nb < 4; ++nb) {
    int d = nb * 16 + ll;
    float sw = subln[d] * ONE_MINUS_LI;
#pragma unroll
    for (int j = 0; j < 4; ++j) {
      int r = (lg << 2) + j;
      o[(orow0 + r) * 1024 + (h << 6) + d] = f2bf(ov[nb][j] * nf[j] * sw);
    }
  }
}

extern "C" void kernel_launch(void* const* d_in, const int* in_sizes, int n_in,
                              void* d_out, int out_size, void* d_ws, size_t ws_size,
                              hipStream_t stream) {
  const float* x      = (const float*)d_in[0];
  const float* W_qkv  = (const float*)d_in[1];
  const float* W_proj = (const float*)d_in[2];
  const float* b_proj = (const float*)d_in[3];
  const float* lq1    = (const float*)d_in[4];
  const float* lk1    = (const float*)d_in[5];
  const float* lq2    = (const float*)d_in[6];
  const float* lk2    = (const float*)d_in[7];
  const float* subln  = (const float*)d_in[8];

  char* ws = (char*)d_ws;
  ushort_t* xb     = (ushort_t*)(ws);                 //  8,388,608 B (4096x1024 bf16)
  ushort_t* qkb    = (ushort_t*)(ws + 8388608);       // 16,777,216 B (4096x2048 bf16, q|k)
  ushort_t* vtb    = (ushort_t*)(ws + 25165824);      //  8,388,608 B (V^T: [2*16*64][2048])
  ushort_t* wqkvT  = (ushort_t*)(ws + 33554432);      //  6,291,456 B (3072x1024 bf16)
  ushort_t* wprojT = (ushort_t*)(ws + 39845888);      //  2,097,152 B (1024x1024 bf16)
  ushort_t* ob     = (ushort_t*)(ws + 41943040);      //  8,388,608 B (4096x1024 bf16)

  cvt_f32_bf16<<<2048, 256, 0, stream>>>(x, xb, 4096 * 1024);
  transpose_to_bf16<<<dim3(96, 32), 256, 0, stream>>>(W_qkv, wqkvT, 1024, 3072);
  transpose_to_bf16<<<dim3(32, 32), 256, 0, stream>>>(W_proj, wprojT, 1024, 1024);
  gemm_bt<1><<<dim3(32, 24), 256, 0, stream>>>(xb, wqkvT, (void*)qkb, vtb, nullptr, 4096, 3072, 1024);
  diff_attn<<<dim3(16, 16, 2), 512, 0, stream>>>(qkb, vtb, ob, lq1, lk1, lq2, lk2, subln);
  gemm_bt<0><<<dim3(32, 8), 256, 0, stream>>>(ob, wprojT, d_out, nullptr, b_proj, 4096, 1024, 1024);
}

// Round 15
// 169.889 us; speedup vs baseline: 1.0186x; 1.0033x over previous
//
#include <hip/hip_runtime.h>

typedef unsigned short ushort_t;
typedef unsigned int uint_t;
typedef __attribute__((ext_vector_type(4))) float f32x4;
typedef __attribute__((ext_vector_type(8))) __bf16 bf16x8;

#define LAMBDA_INIT 0.7836057665316245f
#define ONE_MINUS_LI 0.21639423346837552f
#define QSCALE_LOG2E 0.25505654442552663f  // 32^-0.5 * log2(e)

__device__ inline ushort_t f2bf(float f) {
  union { float f; unsigned u; } v; v.f = f;
  unsigned r = (v.u + 0x7FFFu + ((v.u >> 16) & 1u)) >> 16;
  return (ushort_t)r;
}

// bare v_exp_f32 (args bounded, no libm range fixup needed)
__device__ inline float fexp2(float x) {
  float r;
  asm("v_exp_f32 %0, %1" : "=v"(r) : "v"(x));
  return r;
}

// pack 2 f32 -> 2 bf16 (RNE), lo in low half
__device__ inline uint_t cvtpk(float lo, float hi) {
  uint_t r;
  asm("v_cvt_pk_bf16_f32 %0, %1, %2" : "=v"(r) : "v"(lo), "v"(hi));
  return r;
}

__device__ inline f32x4 zero4() { f32x4 z = {0.f, 0.f, 0.f, 0.f}; return z; }

__device__ inline f32x4 mfma16(bf16x8 a, bf16x8 b, f32x4 c) {
  return __builtin_amdgcn_mfma_f32_16x16x32_bf16(a, b, c, 0, 0, 0);
}

__device__ inline void gload_lds16(const void* g, void* l) {
  __builtin_amdgcn_global_load_lds(
      (const __attribute__((address_space(1))) unsigned int*)g,
      (__attribute__((address_space(3))) unsigned int*)l, 16, 0, 0);
}

// ---------------- convert x (fp32 -> bf16) ----------------
__global__ __launch_bounds__(256) void cvt_f32_bf16(const float* __restrict__ in,
                                                    ushort_t* __restrict__ out, int n) {
  int i = (blockIdx.x * 256 + threadIdx.x) * 8;
  if (i >= n) return;
  float4 a = *(const float4*)(in + i);
  float4 b = *(const float4*)(in + i + 4);
  uint4 pack;
  pack.x = cvtpk(a.x, a.y);
  pack.y = cvtpk(a.z, a.w);
  pack.z = cvtpk(b.x, b.y);
  pack.w = cvtpk(b.z, b.w);
  *(uint4*)(out + i) = pack;
}

// ---------------- transpose W (KxN fp32) -> WT (NxK bf16) ----------------
__global__ __launch_bounds__(256) void transpose_to_bf16(const float* __restrict__ W,
                                                         ushort_t* __restrict__ WT,
                                                         int K, int N) {
  __shared__ float tile[32][33];
  int n0 = blockIdx.x * 32, k0 = blockIdx.y * 32;
  int tx = threadIdx.x & 31, ty = threadIdx.x >> 5;
#pragma unroll
  for (int j = 0; j < 4; ++j) {
    int k = k0 + ty + j * 8;
    tile[ty + j * 8][tx] = W[(size_t)k * N + n0 + tx];
  }
  __syncthreads();
#pragma unroll
  for (int j = 0; j < 4; ++j) {
    int n = n0 + ty + j * 8;
    WT[(size_t)n * K + k0 + tx] = f2bf(tile[tx][ty + j * 8]);
  }
}

// ---------------- GEMM: C[M,N] = A[M,K] * Bt[N,K]^T, bf16 in ----------------
// XCD-aware block swizzle: XCD r hosts contiguous col-panels -> B reuse in L2.
template <int MODE>
__global__ __launch_bounds__(256) void gemm_bt(const ushort_t* __restrict__ A,
                                               const ushort_t* __restrict__ Bt,
                                               void* __restrict__ C,
                                               ushort_t* __restrict__ vt_out,
                                               const float* __restrict__ bias,
                                               int M, int N, int K) {
  __shared__ ushort_t As[128 * 32];
  __shared__ ushort_t Bs[128 * 32];
  const int tid = threadIdx.x;
  const int wave = tid >> 6, lane = tid & 63;
  const int wr = wave >> 1, wc = wave & 1;
  const int lg = lane >> 4, ll = lane & 15;

  // XCD swizzle (nwg divisible by 8: 768 and 256)
  const int lin = blockIdx.x + gridDim.x * blockIdx.y;
  const int cpx = (gridDim.x * gridDim.y) >> 3;
  const int swz = (lin & 7) * cpx + (lin >> 3);
  const int row0 = (swz % gridDim.x) * 128, col0 = (swz / gridDim.x) * 128;

  f32x4 acc[4][4];
#pragma unroll
  for (int m = 0; m < 4; ++m)
#pragma unroll
    for (int n = 0; n < 4; ++n) acc[m][n] = zero4();

  for (int k0 = 0; k0 < K; k0 += 32) {
    __syncthreads();
#pragma unroll
    for (int i = 0; i < 2; ++i) {
      int c = tid + i * 256;
      int r = c >> 2, ko = (c & 3) << 3;
      gload_lds16(A + (size_t)(row0 + r) * K + k0 + ko,
                  (char*)As + (size_t)(wave * 64 + i * 256) * 16);
      gload_lds16(Bt + (size_t)(col0 + r) * K + k0 + ko,
                  (char*)Bs + (size_t)(wave * 64 + i * 256) * 16);
    }
    __syncthreads();
    bf16x8 af[4], bf[4];
#pragma unroll
    for (int m = 0; m < 4; ++m)
      af[m] = *(const bf16x8*)(As + (wr * 64 + m * 16 + ll) * 32 + (lg << 3));
#pragma unroll
    for (int n = 0; n < 4; ++n)
      bf[n] = *(const bf16x8*)(Bs + (wc * 64 + n * 16 + ll) * 32 + (lg << 3));
#pragma unroll
    for (int m = 0; m < 4; ++m)
#pragma unroll
      for (int n = 0; n < 4; ++n) acc[m][n] = mfma16(af[m], bf[n], acc[m][n]);
  }

#pragma unroll
  for (int m = 0; m < 4; ++m) {
#pragma unroll
    for (int n = 0; n < 4; ++n) {
      int gc = col0 + wc * 64 + n * 16 + ll;
      int gr0 = row0 + wr * 64 + m * 16 + (lg << 2);
      if (MODE == 0) {
#pragma unroll
        for (int j = 0; j < 4; ++j)
          ((float*)C)[(size_t)(gr0 + j) * N + gc] = acc[m][n][j] + bias[gc];
      } else {
        if (gc < 2048) {
          float sc = (gc < 1024) ? QSCALE_LOG2E : 1.0f;
#pragma unroll
          for (int j = 0; j < 4; ++j)
            ((ushort_t*)C)[(size_t)(gr0 + j) * 2048 + gc] = f2bf(acc[m][n][j] * sc);
        } else {
          // V columns -> transposed store, 4 consecutive n packed into 8B
          int hv = (gc - 2048) >> 6, dv = (gc - 2048) & 63;
          int bb = gr0 >> 11, nn = gr0 & 2047;
          uint2 w;
          w.x = cvtpk(acc[m][n][0], acc[m][n][1]);
          w.y = cvtpk(acc[m][n][2], acc[m][n][3]);
          *(uint2*)(vt_out + ((size_t)((bb * 16 + hv) * 64 + dv)) * 2048 + nn) = w;
        }
      }
    }
  }
}

// ---------------- differential flash attention (QBLK=128, 8 waves, batched passes) ----------------
// R14 structure with the two passes' chains BATCHED: all kf reads, then all QK
// MFMAs, then all exps, then all P writes (per-pass P regions -- required since
// pass0's P-read now follows pass1's P-writes), one lgkm wait, P reads, all PV
// MFMAs. The two independent chains overlap -> tile critical path ~halves.
__global__ __launch_bounds__(512) void diff_attn(const ushort_t* __restrict__ qk,
                                                 const ushort_t* __restrict__ vt,
                                                 ushort_t* __restrict__ o,
                                                 const float* __restrict__ lq1,
                                                 const float* __restrict__ lk1,
                                                 const float* __restrict__ lq2,
                                                 const float* __restrict__ lk2,
                                                 const float* __restrict__ subln) {
  const int lin = blockIdx.x + (blockIdx.y << 4) + (blockIdx.z << 8);
  const int swz = ((lin & 7) << 6) + (lin >> 3);    // XCD r -> swz in [64r, 64r+64)
  const int qt = swz & 15, h = (swz >> 4) & 15, b = swz >> 8;
  const int tid = threadIdx.x, wave = tid >> 6, lane = tid & 63;
  const int lg = lane >> 4, ll = lane & 15;

  const size_t qbase = (size_t)b * 2048 * 2048;
  const int cq1 = (h << 5), cq2 = 512 + (h << 5);
  const int ck1 = 1024 + (h << 5), ck2 = 1536 + (h << 5);
  const size_t vbase = (size_t)((b * 16 + h) * 64) * 2048;

  float sl1 = 0.f, sl2 = 0.f;
  for (int j = 0; j < 32; ++j) { sl1 += lq1[j] * lk1[j]; sl2 += lq2[j] * lk2[j]; }
  const float lam = __expf(sl1) - __expf(sl2) + LAMBDA_INIT;

  __shared__ ushort_t Ks[2][64 * 64];     // [kv r][8 chunks: 0-3 K1, 4-7 K2], XOR-8 swizzled
  __shared__ ushort_t Vs[2][64 * 64];     // [d r][8 t-chunks], XOR-8 swizzled
  __shared__ ushort_t Pl[8][2][16 * 72];  // per-wave, per-pass P (stride 72, proven affine)

  // Q fragments (B-operand of swapped QK^T); this wave owns q-rows qt*128+wave*16..+15
  const int qrow = qt * 128 + wave * 16 + ll;
  const bf16x8 q1f = *(const bf16x8*)(qk + qbase + (size_t)qrow * 2048 + cq1 + (lg << 3));
  const bf16x8 q2f = *(const bf16x8*)(qk + qbase + (size_t)qrow * 2048 + cq2 + (lg << 3));

  f32x4 o1[4], o2[4];
#pragma unroll
  for (int nb = 0; nb < 4; ++nb) { o1[nb] = zero4(); o2[nb] = zero4(); }
  float l1p = 0.f, l2p = 0.f;
  ushort_t* Pw0 = &Pl[wave][0][0];
  ushort_t* Pw1 = &Pl[wave][1][0];

  // staging: 512 threads, ONE 16B K-slot + ONE 16B V-slot each.
  // slot s=tid -> row r = s>>3, lds chunk s&7 holds global chunk (s&7)^(r&7)
  const int r0 = tid >> 3, c0 = (tid & 7) ^ (r0 & 7);
  const int kc0 = ((c0 & 4) ? ck2 : ck1) + ((c0 & 3) << 3);
  const int ub0 = tid << 4;

#define STAGE(buf, kv0)                                                                   \
  do {                                                                                    \
    gload_lds16(qk + qbase + (size_t)((kv0) + r0) * 2048 + kc0, (char*)Ks[buf] + ub0);    \
    gload_lds16(vt + vbase + (size_t)r0 * 2048 + (kv0) + (c0 << 3), (char*)Vs[buf] + ub0);\
  } while (0)

  auto compute_tile = [&](const ushort_t* Kc, const ushort_t* Vc) {
    // --- all LDS fragment reads (both passes) ---
    bf16x8 vf[2][4];
#pragma unroll
    for (int ks = 0; ks < 2; ++ks)
#pragma unroll
      for (int nb = 0; nb < 4; ++nb)
        vf[ks][nb] = *(const bf16x8*)(Vc + nb * 1024 + ll * 64 + (((ks * 4 + lg) ^ (ll & 7)) << 3));
    const int cK0 = (lg ^ (ll & 7));
    const int cK1 = cK0 ^ 4;
    bf16x8 kf0[4], kf1[4];
#pragma unroll
    for (int nb = 0; nb < 4; ++nb)
      kf0[nb] = *(const bf16x8*)(Kc + nb * 1024 + ll * 64 + (cK0 << 3));
#pragma unroll
    for (int nb = 0; nb < 4; ++nb)
      kf1[nb] = *(const bf16x8*)(Kc + nb * 1024 + ll * 64 + (cK1 << 3));
    // --- all QK MFMAs (both passes) ---
    f32x4 s0[4], s1[4];
    __builtin_amdgcn_s_setprio(1);
#pragma unroll
    for (int nb = 0; nb < 4; ++nb) s0[nb] = mfma16(kf0[nb], q1f, zero4());
#pragma unroll
    for (int nb = 0; nb < 4; ++nb) s1[nb] = mfma16(kf1[nb], q2f, zero4());
    __builtin_amdgcn_s_setprio(0);
    // --- all exps + P writes (both passes) ---
    float part0 = 0.f, part1 = 0.f;
#pragma unroll
    for (int nb = 0; nb < 4; ++nb) {
      float e0 = fexp2(s0[nb][0]), e1 = fexp2(s0[nb][1]);
      float e2 = fexp2(s0[nb][2]), e3 = fexp2(s0[nb][3]);
      part0 += (e0 + e1) + (e2 + e3);
      uint2 w;
      w.x = cvtpk(e0, e1);
      w.y = cvtpk(e2, e3);
      *(uint2*)(Pw0 + ll * 72 + nb * 16 + (lg << 2)) = w;   // P0[q=ll][k=nb*16+4lg..+3]
    }
#pragma unroll
    for (int nb = 0; nb < 4; ++nb) {
      float e0 = fexp2(s1[nb][0]), e1 = fexp2(s1[nb][1]);
      float e2 = fexp2(s1[nb][2]), e3 = fexp2(s1[nb][3]);
      part1 += (e0 + e1) + (e2 + e3);
      uint2 w;
      w.x = cvtpk(e0, e1);
      w.y = cvtpk(e2, e3);
      *(uint2*)(Pw1 + ll * 72 + nb * 16 + (lg << 2)) = w;   // P1[q=ll][k=nb*16+4lg..+3]
    }
    l1p += part0;
    l2p += part1;
    // --- all P reads + PV MFMAs (both passes) ---
    __builtin_amdgcn_s_setprio(1);
#pragma unroll
    for (int ks = 0; ks < 2; ++ks) {
      bf16x8 pf0 = *(const bf16x8*)(Pw0 + ll * 72 + ks * 32 + (lg << 3));
#pragma unroll
      for (int nb = 0; nb < 4; ++nb) o1[nb] = mfma16(pf0, vf[ks][nb], o1[nb]);
      bf16x8 pf1 = *(const bf16x8*)(Pw1 + ll * 72 + ks * 32 + (lg << 3));
#pragma unroll
      for (int nb = 0; nb < 4; ++nb) o2[nb] = mfma16(pf1, vf[ks][nb], o2[nb]);
    }
    __builtin_amdgcn_s_setprio(0);
  };

  STAGE(0, 0);
  __syncthreads();
  for (int tt = 0; tt < 16; ++tt) {
    STAGE(1, (tt * 2 + 1) * 64);
    compute_tile(Ks[0], Vs[0]);
    __syncthreads();
    if (tt < 15) STAGE(0, (tt * 2 + 2) * 64);
    compute_tile(Ks[1], Vs[1]);
    __syncthreads();
  }
#undef STAGE

  // l lives per-lane for q = ll; finish reduction over lg, then fetch per-row.
  float l1 = l1p; l1 += __shfl_xor(l1, 16); l1 += __shfl_xor(l1, 32);
  float l2 = l2p; l2 += __shfl_xor(l2, 16); l2 += __shfl_xor(l2, 32);
  float i1[4], i2[4];
#pragma unroll
  for (int j = 0; j < 4; ++j) {
    int src = (lane & 48) | ((lg << 2) + j);   // lane with ll == q-row
    i1[j] = 1.f / __shfl(l1, src);
    i2[j] = 1.f / __shfl(l2, src);
  }

  float ss[4] = {0.f, 0.f, 0.f, 0.f};
  f32x4 ov[4];
#pragma unroll
  for (int nb = 0; nb < 4; ++nb) {
#pragma unroll
    for (int j = 0; j < 4; ++j) {
      float x = o1[nb][j] * i1[j] - lam * (o2[nb][j] * i2[j]);
      ov[nb][j] = x;
      ss[j] += x * x;
    }
  }
#pragma unroll
  for (int mask = 1; mask < 16; mask <<= 1)
#pragma unroll
    for (int j = 0; j < 4; ++j) ss[j] += __shfl_xor(ss[j], mask);
  float nf[4];
#pragma unroll
  for (int j = 0; j < 4; ++j) nf[j] = rsqrtf(ss[j] * (1.f / 64.f) + 1e-5f);
  const size_t orow0 = (size_t)(b * 2048 + qt * 128 + wave * 16);
#pragma unroll
  for (int nb = 0; nb < 4; ++nb) {
    int d = nb * 16 + ll;
    float sw = subln[d] * ONE_MINUS_LI;
#pragma unroll
    for (int j = 0; j < 4; ++j) {
      int r = (lg << 2) + j;
      o[(orow0 + r) * 1024 + (h << 6) + d] = f2bf(ov[nb][j] * nf[j] * sw);
    }
  }
}

extern "C" void kernel_launch(void* const* d_in, const int* in_sizes, int n_in,
                              void* d_out, int out_size, void* d_ws, size_t ws_size,
                              hipStream_t stream) {
  const float* x      = (const float*)d_in[0];
  const float* W_qkv  = (const float*)d_in[1];
  const float* W_proj = (const float*)d_in[2];
  const float* b_proj = (const float*)d_in[3];
  const float* lq1    = (const float*)d_in[4];
  const float* lk1    = (const float*)d_in[5];
  const float* lq2    = (const float*)d_in[6];
  const float* lk2    = (const float*)d_in[7];
  const float* subln  = (const float*)d_in[8];

  char* ws = (char*)d_ws;
  ushort_t* xb     = (ushort_t*)(ws);                 //  8,388,608 B (4096x1024 bf16)
  ushort_t* qkb    = (ushort_t*)(ws + 8388608);       // 16,777,216 B (4096x2048 bf16, q|k)
  ushort_t* vtb    = (ushort_t*)(ws + 25165824);      //  8,388,608 B (V^T: [2*16*64][2048])
  ushort_t* wqkvT  = (ushort_t*)(ws + 33554432);      //  6,291,456 B (3072x1024 bf16)
  ushort_t* wprojT = (ushort_t*)(ws + 39845888);      //  2,097,152 B (1024x1024 bf16)
  ushort_t* ob     = (ushort_t*)(ws + 41943040);      //  8,388,608 B (4096x1024 bf16)

  cvt_f32_bf16<<<2048, 256, 0, stream>>>(x, xb, 4096 * 1024);
  transpose_to_bf16<<<dim3(96, 32), 256, 0, stream>>>(W_qkv, wqkvT, 1024, 3072);
  transpose_to_bf16<<<dim3(32, 32), 256, 0, stream>>>(W_proj, wprojT, 1024, 1024);
  gemm_bt<1><<<dim3(32, 24), 256, 0, stream>>>(xb, wqkvT, (void*)qkb, vtb, nullptr, 4096, 3072, 1024);
  diff_attn<<<dim3(16, 16, 2), 512, 0, stream>>>(qkb, vtb, ob, lq1, lk1, lq2, lk2, subln);
  gemm_bt<0><<<dim3(32, 8), 256, 0, stream>>>(ob, wprojT, d_out, nullptr, b_proj, 4096, 1024, 1024);
}

// Round 16
// 159.931 us; speedup vs baseline: 1.0820x; 1.0623x over previous
//
#include <hip/hip_runtime.h>

typedef unsigned short ushort_t;
typedef unsigned int uint_t;
typedef __attribute__((ext_vector_type(4))) float f32x4;
typedef __attribute__((ext_vector_type(8))) __bf16 bf16x8;

#define LAMBDA_INIT 0.7836057665316245f
#define ONE_MINUS_LI 0.21639423346837552f
#define QSCALE_LOG2E 0.25505654442552663f  // 32^-0.5 * log2(e)

__device__ inline ushort_t f2bf(float f) {
  union { float f; unsigned u; } v; v.f = f;
  unsigned r = (v.u + 0x7FFFu + ((v.u >> 16) & 1u)) >> 16;
  return (ushort_t)r;
}

// bare v_exp_f32 (args bounded, no libm range fixup needed)
__device__ inline float fexp2(float x) {
  float r;
  asm("v_exp_f32 %0, %1" : "=v"(r) : "v"(x));
  return r;
}

// pack 2 f32 -> 2 bf16 (RNE), lo in low half
__device__ inline uint_t cvtpk(float lo, float hi) {
  uint_t r;
  asm("v_cvt_pk_bf16_f32 %0, %1, %2" : "=v"(r) : "v"(lo), "v"(hi));
  return r;
}

__device__ inline f32x4 zero4() { f32x4 z = {0.f, 0.f, 0.f, 0.f}; return z; }

__device__ inline f32x4 mfma16(bf16x8 a, bf16x8 b, f32x4 c) {
  return __builtin_amdgcn_mfma_f32_16x16x32_bf16(a, b, c, 0, 0, 0);
}

__device__ inline void gload_lds16(const void* g, void* l) {
  __builtin_amdgcn_global_load_lds(
      (const __attribute__((address_space(1))) unsigned int*)g,
      (__attribute__((address_space(3))) unsigned int*)l, 16, 0, 0);
}

// ---------------- convert x (fp32 -> bf16) ----------------
__global__ __launch_bounds__(256) void cvt_f32_bf16(const float* __restrict__ in,
                                                    ushort_t* __restrict__ out, int n) {
  int i = (blockIdx.x * 256 + threadIdx.x) * 8;
  if (i >= n) return;
  float4 a = *(const float4*)(in + i);
  float4 b = *(const float4*)(in + i + 4);
  uint4 pack;
  pack.x = cvtpk(a.x, a.y);
  pack.y = cvtpk(a.z, a.w);
  pack.z = cvtpk(b.x, b.y);
  pack.w = cvtpk(b.z, b.w);
  *(uint4*)(out + i) = pack;
}

// ---------------- transpose W (KxN fp32) -> WT (NxK bf16) ----------------
__global__ __launch_bounds__(256) void transpose_to_bf16(const float* __restrict__ W,
                                                         ushort_t* __restrict__ WT,
                                                         int K, int N) {
  __shared__ float tile[32][33];
  int n0 = blockIdx.x * 32, k0 = blockIdx.y * 32;
  int tx = threadIdx.x & 31, ty = threadIdx.x >> 5;
#pragma unroll
  for (int j = 0; j < 4; ++j) {
    int k = k0 + ty + j * 8;
    tile[ty + j * 8][tx] = W[(size_t)k * N + n0 + tx];
  }
  __syncthreads();
#pragma unroll
  for (int j = 0; j < 4; ++j) {
    int n = n0 + ty + j * 8;
    WT[(size_t)n * K + k0 + tx] = f2bf(tile[tx][ty + j * 8]);
  }
}

// ---------------- GEMM: C[M,N] = A[M,K] * Bt[N,K]^T, bf16 in ----------------
// XCD-aware block swizzle: XCD r hosts contiguous col-panels -> B reuse in L2.
template <int MODE>
__global__ __launch_bounds__(256) void gemm_bt(const ushort_t* __restrict__ A,
                                               const ushort_t* __restrict__ Bt,
                                               void* __restrict__ C,
                                               ushort_t* __restrict__ vt_out,
                                               const float* __restrict__ bias,
                                               int M, int N, int K) {
  __shared__ ushort_t As[128 * 32];
  __shared__ ushort_t Bs[128 * 32];
  const int tid = threadIdx.x;
  const int wave = tid >> 6, lane = tid & 63;
  const int wr = wave >> 1, wc = wave & 1;
  const int lg = lane >> 4, ll = lane & 15;

  // XCD swizzle (nwg divisible by 8: 768 and 256)
  const int lin = blockIdx.x + gridDim.x * blockIdx.y;
  const int cpx = (gridDim.x * gridDim.y) >> 3;
  const int swz = (lin & 7) * cpx + (lin >> 3);
  const int row0 = (swz % gridDim.x) * 128, col0 = (swz / gridDim.x) * 128;

  f32x4 acc[4][4];
#pragma unroll
  for (int m = 0; m < 4; ++m)
#pragma unroll
    for (int n = 0; n < 4; ++n) acc[m][n] = zero4();

  for (int k0 = 0; k0 < K; k0 += 32) {
    __syncthreads();
#pragma unroll
    for (int i = 0; i < 2; ++i) {
      int c = tid + i * 256;
      int r = c >> 2, ko = (c & 3) << 3;
      gload_lds16(A + (size_t)(row0 + r) * K + k0 + ko,
                  (char*)As + (size_t)(wave * 64 + i * 256) * 16);
      gload_lds16(Bt + (size_t)(col0 + r) * K + k0 + ko,
                  (char*)Bs + (size_t)(wave * 64 + i * 256) * 16);
    }
    __syncthreads();
    bf16x8 af[4], bf[4];
#pragma unroll
    for (int m = 0; m < 4; ++m)
      af[m] = *(const bf16x8*)(As + (wr * 64 + m * 16 + ll) * 32 + (lg << 3));
#pragma unroll
    for (int n = 0; n < 4; ++n)
      bf[n] = *(const bf16x8*)(Bs + (wc * 64 + n * 16 + ll) * 32 + (lg << 3));
#pragma unroll
    for (int m = 0; m < 4; ++m)
#pragma unroll
      for (int n = 0; n < 4; ++n) acc[m][n] = mfma16(af[m], bf[n], acc[m][n]);
  }

#pragma unroll
  for (int m = 0; m < 4; ++m) {
#pragma unroll
    for (int n = 0; n < 4; ++n) {
      int gc = col0 + wc * 64 + n * 16 + ll;
      int gr0 = row0 + wr * 64 + m * 16 + (lg << 2);
      if (MODE == 0) {
#pragma unroll
        for (int j = 0; j < 4; ++j)
          ((float*)C)[(size_t)(gr0 + j) * N + gc] = acc[m][n][j] + bias[gc];
      } else {
        if (gc < 2048) {
          float sc = (gc < 1024) ? QSCALE_LOG2E : 1.0f;
#pragma unroll
          for (int j = 0; j < 4; ++j)
            ((ushort_t*)C)[(size_t)(gr0 + j) * 2048 + gc] = f2bf(acc[m][n][j] * sc);
        } else {
          // V columns -> transposed store, 4 consecutive n packed into 8B
          int hv = (gc - 2048) >> 6, dv = (gc - 2048) & 63;
          int bb = gr0 >> 11, nn = gr0 & 2047;
          uint2 w;
          w.x = cvtpk(acc[m][n][0], acc[m][n][1]);
          w.y = cvtpk(acc[m][n][2], acc[m][n][3]);
          *(uint2*)(vt_out + ((size_t)((bb * 16 + hv) * 64 + dv)) * 2048 + nn) = w;
        }
      }
    }
  }
}

// ---------------- differential flash attention (QBLK=128, 8 waves, counted-vmcnt pipeline) ----------------
// Proven R14 per-wave compute (sequential passes, shared per-wave P, affine
// stride-72). Outer schedule: TRIPLE-buffered K/V + raw s_barrier with COUNTED
// vmcnt (never 0 in steady state; m139 precedent). Stage t+2 during tile t:
// buf (t+2)%3 is disjoint from the read buf t%3, and the single barrier per
// tile keeps waves within one iteration -> no race window. Barriers/tile 2->1
// and the global_load_lds queue is never drained.
__global__ __launch_bounds__(512) void diff_attn(const ushort_t* __restrict__ qk,
                                                 const ushort_t* __restrict__ vt,
                                                 ushort_t* __restrict__ o,
                                                 const float* __restrict__ lq1,
                                                 const float* __restrict__ lk1,
                                                 const float* __restrict__ lq2,
                                                 const float* __restrict__ lk2,
                                                 const float* __restrict__ subln) {
  const int lin = blockIdx.x + (blockIdx.y << 4) + (blockIdx.z << 8);
  const int swz = ((lin & 7) << 6) + (lin >> 3);    // XCD r -> swz in [64r, 64r+64)
  const int qt = swz & 15, h = (swz >> 4) & 15, b = swz >> 8;
  const int tid = threadIdx.x, wave = tid >> 6, lane = tid & 63;
  const int lg = lane >> 4, ll = lane & 15;

  const size_t qbase = (size_t)b * 2048 * 2048;
  const int cq1 = (h << 5), cq2 = 512 + (h << 5);
  const int ck1 = 1024 + (h << 5), ck2 = 1536 + (h << 5);
  const size_t vbase = (size_t)((b * 16 + h) * 64) * 2048;

  float sl1 = 0.f, sl2 = 0.f;
  for (int j = 0; j < 32; ++j) { sl1 += lq1[j] * lk1[j]; sl2 += lq2[j] * lk2[j]; }
  const float lam = __expf(sl1) - __expf(sl2) + LAMBDA_INIT;

  __shared__ ushort_t Ks[3][64 * 64];   // triple buffer, XOR-8 swizzled
  __shared__ ushort_t Vs[3][64 * 64];   // triple buffer, XOR-8 swizzled
  __shared__ ushort_t Pl[8][16 * 72];   // per-wave shared P (stride 72, proven affine)

  // Q fragments (B-operand of swapped QK^T); this wave owns q-rows qt*128+wave*16..+15
  const int qrow = qt * 128 + wave * 16 + ll;
  const bf16x8 q1f = *(const bf16x8*)(qk + qbase + (size_t)qrow * 2048 + cq1 + (lg << 3));
  const bf16x8 q2f = *(const bf16x8*)(qk + qbase + (size_t)qrow * 2048 + cq2 + (lg << 3));

  f32x4 o1[4], o2[4];
#pragma unroll
  for (int nb = 0; nb < 4; ++nb) { o1[nb] = zero4(); o2[nb] = zero4(); }
  float l1p = 0.f, l2p = 0.f;
  ushort_t* Pw = &Pl[wave][0];

  // staging: 512 threads, ONE 16B K-slot + ONE 16B V-slot each.
  // slot s=tid -> row r = s>>3, lds chunk s&7 holds global chunk (s&7)^(r&7)
  const int r0 = tid >> 3, c0 = (tid & 7) ^ (r0 & 7);
  const int kc0 = ((c0 & 4) ? ck2 : ck1) + ((c0 & 3) << 3);
  const int ub0 = tid << 4;

#define STAGE(buf, kv0)                                                                   \
  do {                                                                                    \
    gload_lds16(qk + qbase + (size_t)((kv0) + r0) * 2048 + kc0, (char*)Ks[buf] + ub0);    \
    gload_lds16(vt + vbase + (size_t)r0 * 2048 + (kv0) + (c0 << 3), (char*)Vs[buf] + ub0);\
  } while (0)

  auto compute_tile = [&](const ushort_t* Kc, const ushort_t* Vc) {
    bf16x8 vf[2][4];
#pragma unroll
    for (int ks = 0; ks < 2; ++ks)
#pragma unroll
      for (int nb = 0; nb < 4; ++nb)
        vf[ks][nb] = *(const bf16x8*)(Vc + nb * 1024 + ll * 64 + (((ks * 4 + lg) ^ (ll & 7)) << 3));
#pragma unroll
    for (int pass = 0; pass < 2; ++pass) {
      const int cK = (lg ^ (ll & 7)) ^ (pass << 2);
      bf16x8 kf[4];
#pragma unroll
      for (int nb = 0; nb < 4; ++nb)
        kf[nb] = *(const bf16x8*)(Kc + nb * 1024 + ll * 64 + (cK << 3));
      const bf16x8 qf = pass ? q2f : q1f;
      f32x4* oacc = pass ? o2 : o1;
      f32x4 s[4];
      __builtin_amdgcn_s_setprio(1);
#pragma unroll
      for (int nb = 0; nb < 4; ++nb)
        s[nb] = mfma16(kf[nb], qf, zero4());   // D: row=k (4lg+i), col=q (ll)
      __builtin_amdgcn_s_setprio(0);
      float part = 0.f;
#pragma unroll
      for (int nb = 0; nb < 4; ++nb) {
        float e0 = fexp2(s[nb][0]), e1 = fexp2(s[nb][1]);
        float e2 = fexp2(s[nb][2]), e3 = fexp2(s[nb][3]);
        part += (e0 + e1) + (e2 + e3);
        uint2 w;
        w.x = cvtpk(e0, e1);
        w.y = cvtpk(e2, e3);
        // P[q=ll][k = nb*16 + 4lg .. +3]
        *(uint2*)(Pw + ll * 72 + nb * 16 + (lg << 2)) = w;
      }
      if (pass) l2p += part; else l1p += part;
      __builtin_amdgcn_s_setprio(1);
#pragma unroll
      for (int ks = 0; ks < 2; ++ks) {
        bf16x8 pf = *(const bf16x8*)(Pw + ll * 72 + ks * 32 + (lg << 3));
#pragma unroll
        for (int nb = 0; nb < 4; ++nb) oacc[nb] = mfma16(pf, vf[ks][nb], oacc[nb]);
      }
      __builtin_amdgcn_s_setprio(0);
    }
  };

  // prologue: two tiles in flight
  STAGE(0, 0);
  STAGE(1, 64);

  // tile t: wait for t's loads (vmcnt(2): t+1's 2 loads may still fly; 0 at last
  // tile), barrier, compute buf t%3, stage t+2 into buf (t+2)%3.
#define TILE(bufc, bufn, t)                                                               \
  do {                                                                                    \
    if ((t) < 31) asm volatile("s_waitcnt vmcnt(2)" ::: "memory");                        \
    else          asm volatile("s_waitcnt vmcnt(0)" ::: "memory");                        \
    __builtin_amdgcn_s_barrier();                                                         \
    __builtin_amdgcn_sched_barrier(0);                                                    \
    compute_tile(Ks[bufc], Vs[bufc]);                                                     \
    if ((t) + 2 < 32) STAGE(bufn, ((t) + 2) * 64);                                        \
  } while (0)

  for (int base = 0; base < 30; base += 3) {
    TILE(0, 2, base);
    TILE(1, 0, base + 1);
    TILE(2, 1, base + 2);
  }
  TILE(0, 2, 30);
  TILE(1, 0, 31);
#undef TILE
#undef STAGE

  // l lives per-lane for q = ll; finish reduction over lg, then fetch per-row.
  float l1 = l1p; l1 += __shfl_xor(l1, 16); l1 += __shfl_xor(l1, 32);
  float l2 = l2p; l2 += __shfl_xor(l2, 16); l2 += __shfl_xor(l2, 32);
  float i1[4], i2[4];
#pragma unroll
  for (int j = 0; j < 4; ++j) {
    int src = (lane & 48) | ((lg << 2) + j);   // lane with ll == q-row
    i1[j] = 1.f / __shfl(l1, src);
    i2[j] = 1.f / __shfl(l2, src);
  }

  float ss[4] = {0.f, 0.f, 0.f, 0.f};
  f32x4 ov[4];
#pragma unroll
  for (int nb = 0; nb < 4; ++nb) {
#pragma unroll
    for (int j = 0; j < 4; ++j) {
      float x = o1[nb][j] * i1[j] - lam * (o2[nb][j] * i2[j]);
      ov[nb][j] = x;
      ss[j] += x * x;
    }
  }
#pragma unroll
  for (int mask = 1; mask < 16; mask <<= 1)
#pragma unroll
    for (int j = 0; j < 4; ++j) ss[j] += __shfl_xor(ss[j], mask);
  float nf[4];
#pragma unroll
  for (int j = 0; j < 4; ++j) nf[j] = rsqrtf(ss[j] * (1.f / 64.f) + 1e-5f);
  const size_t orow0 = (size_t)(b * 2048 + qt * 128 + wave * 16);
#pragma unroll
  for (int nb = 0; nb < 4; ++nb) {
    int d = nb * 16 + ll;
    float sw = subln[d] * ONE_MINUS_LI;
#pragma unroll
    for (int j = 0; j < 4; ++j) {
      int r = (lg << 2) + j;
      o[(orow0 + r) * 1024 + (h << 6) + d] = f2bf(ov[nb][j] * nf[j] * sw);
    }
  }
}

extern "C" void kernel_launch(void* const* d_in, const int* in_sizes, int n_in,
                              void* d_out, int out_size, void* d_ws, size_t ws_size,
                              hipStream_t stream) {
  const float* x      = (const float*)d_in[0];
  const float* W_qkv  = (const float*)d_in[1];
  const float* W_proj = (const float*)d_in[2];
  const float* b_proj = (const float*)d_in[3];
  const float* lq1    = (const float*)d_in[4];
  const float* lk1    = (const float*)d_in[5];
  const float* lq2    = (const float*)d_in[6];
  const float* lk2    = (const float*)d_in[7];
  const float* subln  = (const float*)d_in[8];

  char* ws = (char*)d_ws;
  ushort_t* xb     = (ushort_t*)(ws);                 //  8,388,608 B (4096x1024 bf16)
  ushort_t* qkb    = (ushort_t*)(ws + 8388608);       // 16,777,216 B (4096x2048 bf16, q|k)
  ushort_t* vtb    = (ushort_t*)(ws + 25165824);      //  8,388,608 B (V^T: [2*16*64][2048])
  ushort_t* wqkvT  = (ushort_t*)(ws + 33554432);      //  6,291,456 B (3072x1024 bf16)
  ushort_t* wprojT = (ushort_t*)(ws + 39845888);      //  2,097,152 B (1024x1024 bf16)
  ushort_t* ob     = (ushort_t*)(ws + 41943040);      //  8,388,608 B (4096x1024 bf16)

  cvt_f32_bf16<<<2048, 256, 0, stream>>>(x, xb, 4096 * 1024);
  transpose_to_bf16<<<dim3(96, 32), 256, 0, stream>>>(W_qkv, wqkvT, 1024, 3072);
  transpose_to_bf16<<<dim3(32, 32), 256, 0, stream>>>(W_proj, wprojT, 1024, 1024);
  gemm_bt<1><<<dim3(32, 24), 256, 0, stream>>>(xb, wqkvT, (void*)qkb, vtb, nullptr, 4096, 3072, 1024);
  diff_attn<<<dim3(16, 16, 2), 512, 0, stream>>>(qkb, vtb, ob, lq1, lk1, lq2, lk2, subln);
  gemm_bt<0><<<dim3(32, 8), 256, 0, stream>>>(ob, wprojT, d_out, nullptr, b_proj, 4096, 1024, 1024);
}

// Round 17
// 143.917 us; speedup vs baseline: 1.2024x; 1.1113x over previous
//
#include <hip/hip_runtime.h>

typedef unsigned short ushort_t;
typedef unsigned int uint_t;
typedef __attribute__((ext_vector_type(4))) float f32x4;
typedef __attribute__((ext_vector_type(8))) __bf16 bf16x8;

#define LAMBDA_INIT 0.7836057665316245f
#define ONE_MINUS_LI 0.21639423346837552f
#define QSCALE_LOG2E 0.25505654442552663f  // 32^-0.5 * log2(e)

__device__ inline ushort_t f2bf(float f) {
  union { float f; unsigned u; } v; v.f = f;
  unsigned r = (v.u + 0x7FFFu + ((v.u >> 16) & 1u)) >> 16;
  return (ushort_t)r;
}

// bare v_exp_f32 (args bounded, no libm range fixup needed)
__device__ inline float fexp2(float x) {
  float r;
  asm("v_exp_f32 %0, %1" : "=v"(r) : "v"(x));
  return r;
}

// pack 2 f32 -> 2 bf16 (RNE), lo in low half
__device__ inline uint_t cvtpk(float lo, float hi) {
  uint_t r;
  asm("v_cvt_pk_bf16_f32 %0, %1, %2" : "=v"(r) : "v"(lo), "v"(hi));
  return r;
}

__device__ inline f32x4 zero4() { f32x4 z = {0.f, 0.f, 0.f, 0.f}; return z; }

__device__ inline f32x4 mfma16(bf16x8 a, bf16x8 b, f32x4 c) {
  return __builtin_amdgcn_mfma_f32_16x16x32_bf16(a, b, c, 0, 0, 0);
}

__device__ inline void gload_lds16(const void* g, void* l) {
  __builtin_amdgcn_global_load_lds(
      (const __attribute__((address_space(1))) unsigned int*)g,
      (__attribute__((address_space(3))) unsigned int*)l, 16, 0, 0);
}

// ---------------- convert x (fp32 -> bf16) ----------------
__global__ __launch_bounds__(256) void cvt_f32_bf16(const float* __restrict__ in,
                                                    ushort_t* __restrict__ out, int n) {
  int i = (blockIdx.x * 256 + threadIdx.x) * 8;
  if (i >= n) return;
  float4 a = *(const float4*)(in + i);
  float4 b = *(const float4*)(in + i + 4);
  uint4 pack;
  pack.x = cvtpk(a.x, a.y);
  pack.y = cvtpk(a.z, a.w);
  pack.z = cvtpk(b.x, b.y);
  pack.w = cvtpk(b.z, b.w);
  *(uint4*)(out + i) = pack;
}

// ---------------- transpose W (KxN fp32) -> WT (NxK bf16) ----------------
__global__ __launch_bounds__(256) void transpose_to_bf16(const float* __restrict__ W,
                                                         ushort_t* __restrict__ WT,
                                                         int K, int N) {
  __shared__ float tile[32][33];
  int n0 = blockIdx.x * 32, k0 = blockIdx.y * 32;
  int tx = threadIdx.x & 31, ty = threadIdx.x >> 5;
#pragma unroll
  for (int j = 0; j < 4; ++j) {
    int k = k0 + ty + j * 8;
    tile[ty + j * 8][tx] = W[(size_t)k * N + n0 + tx];
  }
  __syncthreads();
#pragma unroll
  for (int j = 0; j < 4; ++j) {
    int n = n0 + ty + j * 8;
    WT[(size_t)n * K + k0 + tx] = f2bf(tile[tx][ty + j * 8]);
  }
}

// ---------------- GEMM: C[M,N] = A[M,K] * Bt[N,K]^T, bf16 in, K must be 1024 ----------------
// XCD-aware block swizzle + counted-vmcnt triple-buffer pipeline (the pattern
// proven on diff_attn in R16): raw s_barrier with vmcnt(4) in steady state
// (4 loads/thread/K-step; next tile's 4 stay in flight), vmcnt(0) only at the
// final tile. Barriers/K-step 2->1, global_load_lds queue never drains.
template <int MODE>
__global__ __launch_bounds__(256) void gemm_bt(const ushort_t* __restrict__ A,
                                               const ushort_t* __restrict__ Bt,
                                               void* __restrict__ C,
                                               ushort_t* __restrict__ vt_out,
                                               const float* __restrict__ bias,
                                               int M, int N, int K) {
  __shared__ ushort_t As[3][128 * 32];
  __shared__ ushort_t Bs[3][128 * 32];
  const int tid = threadIdx.x;
  const int wave = tid >> 6, lane = tid & 63;
  const int wr = wave >> 1, wc = wave & 1;
  const int lg = lane >> 4, ll = lane & 15;

  // XCD swizzle (nwg divisible by 8: 768 and 256)
  const int lin = blockIdx.x + gridDim.x * blockIdx.y;
  const int cpx = (gridDim.x * gridDim.y) >> 3;
  const int swz = (lin & 7) * cpx + (lin >> 3);
  const int row0 = (swz % gridDim.x) * 128, col0 = (swz / gridDim.x) * 128;

  f32x4 acc[4][4];
#pragma unroll
  for (int m = 0; m < 4; ++m)
#pragma unroll
    for (int n = 0; n < 4; ++n) acc[m][n] = zero4();

  // staging geometry: slot c -> row r=c>>2, k-chunk (c&3)*8
  const int ra = tid >> 2, ka = (tid & 3) << 3;
  const int rb = (tid + 256) >> 2, kb = ((tid + 256) & 3) << 3;
  const int ua = (wave * 64) * 16;            // slots [wave*64, +64)
  const int ub = (wave * 64 + 256) * 16;      // slots [256+wave*64, +64)

#define GSTAGE(buf, k0)                                                              \
  do {                                                                               \
    gload_lds16(A + (size_t)(row0 + ra) * K + (k0) + ka, (char*)As[buf] + ua);       \
    gload_lds16(Bt + (size_t)(col0 + ra) * K + (k0) + ka, (char*)Bs[buf] + ua);      \
    gload_lds16(A + (size_t)(row0 + rb) * K + (k0) + kb, (char*)As[buf] + ub);       \
    gload_lds16(Bt + (size_t)(col0 + rb) * K + (k0) + kb, (char*)Bs[buf] + ub);      \
  } while (0)

  auto gcompute = [&](const ushort_t* Ac, const ushort_t* Bc) {
    bf16x8 af[4], bf[4];
#pragma unroll
    for (int m = 0; m < 4; ++m)
      af[m] = *(const bf16x8*)(Ac + (wr * 64 + m * 16 + ll) * 32 + (lg << 3));
#pragma unroll
    for (int n = 0; n < 4; ++n)
      bf[n] = *(const bf16x8*)(Bc + (wc * 64 + n * 16 + ll) * 32 + (lg << 3));
    __builtin_amdgcn_s_setprio(1);
#pragma unroll
    for (int m = 0; m < 4; ++m)
#pragma unroll
      for (int n = 0; n < 4; ++n) acc[m][n] = mfma16(af[m], bf[n], acc[m][n]);
    __builtin_amdgcn_s_setprio(0);
  };

  // prologue: two K-steps in flight (K = 1024 -> 32 steps)
  GSTAGE(0, 0);
  GSTAGE(1, 32);

#define GTILE(bufc, bufn, t)                                                         \
  do {                                                                               \
    if ((t) < 31) asm volatile("s_waitcnt vmcnt(4)" ::: "memory");                   \
    else          asm volatile("s_waitcnt vmcnt(0)" ::: "memory");                   \
    __builtin_amdgcn_s_barrier();                                                    \
    __builtin_amdgcn_sched_barrier(0);                                               \
    gcompute(As[bufc], Bs[bufc]);                                                    \
    if ((t) + 2 < 32) GSTAGE(bufn, ((t) + 2) * 32);                                  \
  } while (0)

  for (int base = 0; base < 30; base += 3) {
    GTILE(0, 2, base);
    GTILE(1, 0, base + 1);
    GTILE(2, 1, base + 2);
  }
  GTILE(0, 2, 30);
  GTILE(1, 0, 31);
#undef GTILE
#undef GSTAGE

#pragma unroll
  for (int m = 0; m < 4; ++m) {
#pragma unroll
    for (int n = 0; n < 4; ++n) {
      int gc = col0 + wc * 64 + n * 16 + ll;
      int gr0 = row0 + wr * 64 + m * 16 + (lg << 2);
      if (MODE == 0) {
#pragma unroll
        for (int j = 0; j < 4; ++j)
          ((float*)C)[(size_t)(gr0 + j) * N + gc] = acc[m][n][j] + bias[gc];
      } else {
        if (gc < 2048) {
          float sc = (gc < 1024) ? QSCALE_LOG2E : 1.0f;
#pragma unroll
          for (int j = 0; j < 4; ++j)
            ((ushort_t*)C)[(size_t)(gr0 + j) * 2048 + gc] = f2bf(acc[m][n][j] * sc);
        } else {
          // V columns -> transposed store, 4 consecutive n packed into 8B
          int hv = (gc - 2048) >> 6, dv = (gc - 2048) & 63;
          int bb = gr0 >> 11, nn = gr0 & 2047;
          uint2 w;
          w.x = cvtpk(acc[m][n][0], acc[m][n][1]);
          w.y = cvtpk(acc[m][n][2], acc[m][n][3]);
          *(uint2*)(vt_out + ((size_t)((bb * 16 + hv) * 64 + dv)) * 2048 + nn) = w;
        }
      }
    }
  }
}

// ---------------- differential flash attention (QBLK=128, 8 waves, counted-vmcnt pipeline) ----------------
// R16 kernel, UNCHANGED (proven 84.8us): triple-buffered K/V + raw s_barrier
// with counted vmcnt (never 0 in steady state), sequential passes, shared
// per-wave P (affine stride 72).
__global__ __launch_bounds__(512) void diff_attn(const ushort_t* __restrict__ qk,
                                                 const ushort_t* __restrict__ vt,
                                                 ushort_t* __restrict__ o,
                                                 const float* __restrict__ lq1,
                                                 const float* __restrict__ lk1,
                                                 const float* __restrict__ lq2,
                                                 const float* __restrict__ lk2,
                                                 const float* __restrict__ subln) {
  const int lin = blockIdx.x + (blockIdx.y << 4) + (blockIdx.z << 8);
  const int swz = ((lin & 7) << 6) + (lin >> 3);    // XCD r -> swz in [64r, 64r+64)
  const int qt = swz & 15, h = (swz >> 4) & 15, b = swz >> 8;
  const int tid = threadIdx.x, wave = tid >> 6, lane = tid & 63;
  const int lg = lane >> 4, ll = lane & 15;

  const size_t qbase = (size_t)b * 2048 * 2048;
  const int cq1 = (h << 5), cq2 = 512 + (h << 5);
  const int ck1 = 1024 + (h << 5), ck2 = 1536 + (h << 5);
  const size_t vbase = (size_t)((b * 16 + h) * 64) * 2048;

  float sl1 = 0.f, sl2 = 0.f;
  for (int j = 0; j < 32; ++j) { sl1 += lq1[j] * lk1[j]; sl2 += lq2[j] * lk2[j]; }
  const float lam = __expf(sl1) - __expf(sl2) + LAMBDA_INIT;

  __shared__ ushort_t Ks[3][64 * 64];   // triple buffer, XOR-8 swizzled
  __shared__ ushort_t Vs[3][64 * 64];   // triple buffer, XOR-8 swizzled
  __shared__ ushort_t Pl[8][16 * 72];   // per-wave shared P (stride 72, proven affine)

  // Q fragments (B-operand of swapped QK^T); this wave owns q-rows qt*128+wave*16..+15
  const int qrow = qt * 128 + wave * 16 + ll;
  const bf16x8 q1f = *(const bf16x8*)(qk + qbase + (size_t)qrow * 2048 + cq1 + (lg << 3));
  const bf16x8 q2f = *(const bf16x8*)(qk + qbase + (size_t)qrow * 2048 + cq2 + (lg << 3));

  f32x4 o1[4], o2[4];
#pragma unroll
  for (int nb = 0; nb < 4; ++nb) { o1[nb] = zero4(); o2[nb] = zero4(); }
  float l1p = 0.f, l2p = 0.f;
  ushort_t* Pw = &Pl[wave][0];

  // staging: 512 threads, ONE 16B K-slot + ONE 16B V-slot each.
  // slot s=tid -> row r = s>>3, lds chunk s&7 holds global chunk (s&7)^(r&7)
  const int r0 = tid >> 3, c0 = (tid & 7) ^ (r0 & 7);
  const int kc0 = ((c0 & 4) ? ck2 : ck1) + ((c0 & 3) << 3);
  const int ub0 = tid << 4;

#define STAGE(buf, kv0)                                                                   \
  do {                                                                                    \
    gload_lds16(qk + qbase + (size_t)((kv0) + r0) * 2048 + kc0, (char*)Ks[buf] + ub0);    \
    gload_lds16(vt + vbase + (size_t)r0 * 2048 + (kv0) + (c0 << 3), (char*)Vs[buf] + ub0);\
  } while (0)

  auto compute_tile = [&](const ushort_t* Kc, const ushort_t* Vc) {
    bf16x8 vf[2][4];
#pragma unroll
    for (int ks = 0; ks < 2; ++ks)
#pragma unroll
      for (int nb = 0; nb < 4; ++nb)
        vf[ks][nb] = *(const bf16x8*)(Vc + nb * 1024 + ll * 64 + (((ks * 4 + lg) ^ (ll & 7)) << 3));
#pragma unroll
    for (int pass = 0; pass < 2; ++pass) {
      const int cK = (lg ^ (ll & 7)) ^ (pass << 2);
      bf16x8 kf[4];
#pragma unroll
      for (int nb = 0; nb < 4; ++nb)
        kf[nb] = *(const bf16x8*)(Kc + nb * 1024 + ll * 64 + (cK << 3));
      const bf16x8 qf = pass ? q2f : q1f;
      f32x4* oacc = pass ? o2 : o1;
      f32x4 s[4];
      __builtin_amdgcn_s_setprio(1);
#pragma unroll
      for (int nb = 0; nb < 4; ++nb)
        s[nb] = mfma16(kf[nb], qf, zero4());   // D: row=k (4lg+i), col=q (ll)
      __builtin_amdgcn_s_setprio(0);
      float part = 0.f;
#pragma unroll
      for (int nb = 0; nb < 4; ++nb) {
        float e0 = fexp2(s[nb][0]), e1 = fexp2(s[nb][1]);
        float e2 = fexp2(s[nb][2]), e3 = fexp2(s[nb][3]);
        part += (e0 + e1) + (e2 + e3);
        uint2 w;
        w.x = cvtpk(e0, e1);
        w.y = cvtpk(e2, e3);
        // P[q=ll][k = nb*16 + 4lg .. +3]
        *(uint2*)(Pw + ll * 72 + nb * 16 + (lg << 2)) = w;
      }
      if (pass) l2p += part; else l1p += part;
      __builtin_amdgcn_s_setprio(1);
#pragma unroll
      for (int ks = 0; ks < 2; ++ks) {
        bf16x8 pf = *(const bf16x8*)(Pw + ll * 72 + ks * 32 + (lg << 3));
#pragma unroll
        for (int nb = 0; nb < 4; ++nb) oacc[nb] = mfma16(pf, vf[ks][nb], oacc[nb]);
      }
      __builtin_amdgcn_s_setprio(0);
    }
  };

  // prologue: two tiles in flight
  STAGE(0, 0);
  STAGE(1, 64);

#define TILE(bufc, bufn, t)                                                               \
  do {                                                                                    \
    if ((t) < 31) asm volatile("s_waitcnt vmcnt(2)" ::: "memory");                        \
    else          asm volatile("s_waitcnt vmcnt(0)" ::: "memory");                        \
    __builtin_amdgcn_s_barrier();                                                         \
    __builtin_amdgcn_sched_barrier(0);                                                    \
    compute_tile(Ks[bufc], Vs[bufc]);                                                     \
    if ((t) + 2 < 32) STAGE(bufn, ((t) + 2) * 64);                                        \
  } while (0)

  for (int base = 0; base < 30; base += 3) {
    TILE(0, 2, base);
    TILE(1, 0, base + 1);
    TILE(2, 1, base + 2);
  }
  TILE(0, 2, 30);
  TILE(1, 0, 31);
#undef TILE
#undef STAGE

  // l lives per-lane for q = ll; finish reduction over lg, then fetch per-row.
  float l1 = l1p; l1 += __shfl_xor(l1, 16); l1 += __shfl_xor(l1, 32);
  float l2 = l2p; l2 += __shfl_xor(l2, 16); l2 += __shfl_xor(l2, 32);
  float i1[4], i2[4];
#pragma unroll
  for (int j = 0; j < 4; ++j) {
    int src = (lane & 48) | ((lg << 2) + j);   // lane with ll == q-row
    i1[j] = 1.f / __shfl(l1, src);
    i2[j] = 1.f / __shfl(l2, src);
  }

  float ss[4] = {0.f, 0.f, 0.f, 0.f};
  f32x4 ov[4];
#pragma unroll
  for (int nb = 0; nb < 4; ++nb) {
#pragma unroll
    for (int j = 0; j < 4; ++j) {
      float x = o1[nb][j] * i1[j] - lam * (o2[nb][j] * i2[j]);
      ov[nb][j] = x;
      ss[j] += x * x;
    }
  }
#pragma unroll
  for (int mask = 1; mask < 16; mask <<= 1)
#pragma unroll
    for (int j = 0; j < 4; ++j) ss[j] += __shfl_xor(ss[j], mask);
  float nf[4];
#pragma unroll
  for (int j = 0; j < 4; ++j) nf[j] = rsqrtf(ss[j] * (1.f / 64.f) + 1e-5f);
  const size_t orow0 = (size_t)(b * 2048 + qt * 128 + wave * 16);
#pragma unroll
  for (int nb = 0; nb < 4; ++nb) {
    int d = nb * 16 + ll;
    float sw = subln[d] * ONE_MINUS_LI;
#pragma unroll
    for (int j = 0; j < 4; ++j) {
      int r = (lg << 2) + j;
      o[(orow0 + r) * 1024 + (h << 6) + d] = f2bf(ov[nb][j] * nf[j] * sw);
    }
  }
}

extern "C" void kernel_launch(void* const* d_in, const int* in_sizes, int n_in,
                              void* d_out, int out_size, void* d_ws, size_t ws_size,
                              hipStream_t stream) {
  const float* x      = (const float*)d_in[0];
  const float* W_qkv  = (const float*)d_in[1];
  const float* W_proj = (const float*)d_in[2];
  const float* b_proj = (const float*)d_in[3];
  const float* lq1    = (const float*)d_in[4];
  const float* lk1    = (const float*)d_in[5];
  const float* lq2    = (const float*)d_in[6];
  const float* lk2    = (const float*)d_in[7];
  const float* subln  = (const float*)d_in[8];

  char* ws = (char*)d_ws;
  ushort_t* xb     = (ushort_t*)(ws);                 //  8,388,608 B (4096x1024 bf16)
  ushort_t* qkb    = (ushort_t*)(ws + 8388608);       // 16,777,216 B (4096x2048 bf16, q|k)
  ushort_t* vtb    = (ushort_t*)(ws + 25165824);      //  8,388,608 B (V^T: [2*16*64][2048])
  ushort_t* wqkvT  = (ushort_t*)(ws + 33554432);      //  6,291,456 B (3072x1024 bf16)
  ushort_t* wprojT = (ushort_t*)(ws + 39845888);      //  2,097,152 B (1024x1024 bf16)
  ushort_t* ob     = (ushort_t*)(ws + 41943040);      //  8,388,608 B (4096x1024 bf16)

  cvt_f32_bf16<<<2048, 256, 0, stream>>>(x, xb, 4096 * 1024);
  transpose_to_bf16<<<dim3(96, 32), 256, 0, stream>>>(W_qkv, wqkvT, 1024, 3072);
  transpose_to_bf16<<<dim3(32, 32), 256, 0, stream>>>(W_proj, wprojT, 1024, 1024);
  gemm_bt<1><<<dim3(32, 24), 256, 0, stream>>>(xb, wqkvT, (void*)qkb, vtb, nullptr, 4096, 3072, 1024);
  diff_attn<<<dim3(16, 16, 2), 512, 0, stream>>>(qkb, vtb, ob, lq1, lk1, lq2, lk2, subln);
  gemm_bt<0><<<dim3(32, 8), 256, 0, stream>>>(ob, wprojT, d_out, nullptr, b_proj, 4096, 1024, 1024);
}

// Round 18
// 139.294 us; speedup vs baseline: 1.2423x; 1.0332x over previous
//
#include <hip/hip_runtime.h>

typedef unsigned short ushort_t;
typedef unsigned int uint_t;
typedef __attribute__((ext_vector_type(4))) float f32x4;
typedef __attribute__((ext_vector_type(8))) __bf16 bf16x8;

#define LAMBDA_INIT 0.7836057665316245f
#define ONE_MINUS_LI 0.21639423346837552f
#define QSCALE_LOG2E 0.25505654442552663f  // 32^-0.5 * log2(e)

__device__ inline ushort_t f2bf(float f) {
  union { float f; unsigned u; } v; v.f = f;
  unsigned r = (v.u + 0x7FFFu + ((v.u >> 16) & 1u)) >> 16;
  return (ushort_t)r;
}

// bare v_exp_f32 (args bounded, no libm range fixup needed)
__device__ inline float fexp2(float x) {
  float r;
  asm("v_exp_f32 %0, %1" : "=v"(r) : "v"(x));
  return r;
}

// pack 2 f32 -> 2 bf16 (RNE), lo in low half
__device__ inline uint_t cvtpk(float lo, float hi) {
  uint_t r;
  asm("v_cvt_pk_bf16_f32 %0, %1, %2" : "=v"(r) : "v"(lo), "v"(hi));
  return r;
}

__device__ inline f32x4 zero4() { f32x4 z = {0.f, 0.f, 0.f, 0.f}; return z; }

__device__ inline f32x4 mfma16(bf16x8 a, bf16x8 b, f32x4 c) {
  return __builtin_amdgcn_mfma_f32_16x16x32_bf16(a, b, c, 0, 0, 0);
}

__device__ inline void gload_lds16(const void* g, void* l) {
  __builtin_amdgcn_global_load_lds(
      (const __attribute__((address_space(1))) unsigned int*)g,
      (__attribute__((address_space(3))) unsigned int*)l, 16, 0, 0);
}

// ---------------- fused prologue: cvt(x) || transpose(W_qkv) || transpose(W_proj) ----------------
// The three prologue jobs are independent; fusing them into one launch lets
// them run CONCURRENTLY (serial sum ~10us -> ~max 6.5us) and drops 2 launches.
// blocks [0,2048): cvt x -> xb (bf16)
// blocks [2048,5120): transpose W_qkv (1024x3072 f32) -> wqkvT (3072x1024 bf16)
// blocks [5120,6144): transpose W_proj (1024x1024 f32) -> wprojT (1024x1024 bf16)
__global__ __launch_bounds__(256) void prep(const float* __restrict__ x,
                                            ushort_t* __restrict__ xb,
                                            const float* __restrict__ Wqkv,
                                            ushort_t* __restrict__ wqkvT,
                                            const float* __restrict__ Wproj,
                                            ushort_t* __restrict__ wprojT) {
  __shared__ float tile[32][33];
  const int bx = blockIdx.x;
  if (bx < 2048) {
    int i = (bx * 256 + threadIdx.x) * 8;
    float4 a = *(const float4*)(x + i);
    float4 b = *(const float4*)(x + i + 4);
    uint4 pack;
    pack.x = cvtpk(a.x, a.y);
    pack.y = cvtpk(a.z, a.w);
    pack.z = cvtpk(b.x, b.y);
    pack.w = cvtpk(b.z, b.w);
    *(uint4*)(xb + i) = pack;
    return;
  }
  const float* W;
  ushort_t* WT;
  int n0, k0, N;
  if (bx < 5120) {
    int t = bx - 2048;
    W = Wqkv; WT = wqkvT; N = 3072;
    n0 = (t % 96) * 32; k0 = (t / 96) * 32;
  } else {
    int t = bx - 5120;
    W = Wproj; WT = wprojT; N = 1024;
    n0 = (t & 31) * 32; k0 = (t >> 5) * 32;
  }
  const int K = 1024;
  int tx = threadIdx.x & 31, ty = threadIdx.x >> 5;
#pragma unroll
  for (int j = 0; j < 4; ++j) {
    int k = k0 + ty + j * 8;
    tile[ty + j * 8][tx] = W[(size_t)k * N + n0 + tx];
  }
  __syncthreads();
#pragma unroll
  for (int j = 0; j < 4; ++j) {
    int n = n0 + ty + j * 8;
    WT[(size_t)n * K + k0 + tx] = f2bf(tile[tx][ty + j * 8]);
  }
}

// ---------------- GEMM: C[M,N] = A[M,K] * Bt[N,K]^T, bf16 in, K must be 1024 ----------------
// XCD-aware block swizzle + counted-vmcnt triple-buffer pipeline (proven R16/R17):
// raw s_barrier with vmcnt(4) in steady state, vmcnt(0) only at the final tile.
template <int MODE>
__global__ __launch_bounds__(256) void gemm_bt(const ushort_t* __restrict__ A,
                                               const ushort_t* __restrict__ Bt,
                                               void* __restrict__ C,
                                               ushort_t* __restrict__ vt_out,
                                               const float* __restrict__ bias,
                                               int M, int N, int K) {
  __shared__ ushort_t As[3][128 * 32];
  __shared__ ushort_t Bs[3][128 * 32];
  const int tid = threadIdx.x;
  const int wave = tid >> 6, lane = tid & 63;
  const int wr = wave >> 1, wc = wave & 1;
  const int lg = lane >> 4, ll = lane & 15;

  // XCD swizzle (nwg divisible by 8: 768 and 256)
  const int lin = blockIdx.x + gridDim.x * blockIdx.y;
  const int cpx = (gridDim.x * gridDim.y) >> 3;
  const int swz = (lin & 7) * cpx + (lin >> 3);
  const int row0 = (swz % gridDim.x) * 128, col0 = (swz / gridDim.x) * 128;

  f32x4 acc[4][4];
#pragma unroll
  for (int m = 0; m < 4; ++m)
#pragma unroll
    for (int n = 0; n < 4; ++n) acc[m][n] = zero4();

  // staging geometry: slot c -> row r=c>>2, k-chunk (c&3)*8
  const int ra = tid >> 2, ka = (tid & 3) << 3;
  const int rb = (tid + 256) >> 2, kb = ((tid + 256) & 3) << 3;
  const int ua = (wave * 64) * 16;            // slots [wave*64, +64)
  const int ub = (wave * 64 + 256) * 16;      // slots [256+wave*64, +64)

#define GSTAGE(buf, k0)                                                              \
  do {                                                                               \
    gload_lds16(A + (size_t)(row0 + ra) * K + (k0) + ka, (char*)As[buf] + ua);       \
    gload_lds16(Bt + (size_t)(col0 + ra) * K + (k0) + ka, (char*)Bs[buf] + ua);      \
    gload_lds16(A + (size_t)(row0 + rb) * K + (k0) + kb, (char*)As[buf] + ub);       \
    gload_lds16(Bt + (size_t)(col0 + rb) * K + (k0) + kb, (char*)Bs[buf] + ub);      \
  } while (0)

  auto gcompute = [&](const ushort_t* Ac, const ushort_t* Bc) {
    bf16x8 af[4], bf[4];
#pragma unroll
    for (int m = 0; m < 4; ++m)
      af[m] = *(const bf16x8*)(Ac + (wr * 64 + m * 16 + ll) * 32 + (lg << 3));
#pragma unroll
    for (int n = 0; n < 4; ++n)
      bf[n] = *(const bf16x8*)(Bc + (wc * 64 + n * 16 + ll) * 32 + (lg << 3));
    __builtin_amdgcn_s_setprio(1);
#pragma unroll
    for (int m = 0; m < 4; ++m)
#pragma unroll
      for (int n = 0; n < 4; ++n) acc[m][n] = mfma16(af[m], bf[n], acc[m][n]);
    __builtin_amdgcn_s_setprio(0);
  };

  // prologue: two K-steps in flight (K = 1024 -> 32 steps)
  GSTAGE(0, 0);
  GSTAGE(1, 32);

#define GTILE(bufc, bufn, t)                                                         \
  do {                                                                               \
    if ((t) < 31) asm volatile("s_waitcnt vmcnt(4)" ::: "memory");                   \
    else          asm volatile("s_waitcnt vmcnt(0)" ::: "memory");                   \
    __builtin_amdgcn_s_barrier();                                                    \
    __builtin_amdgcn_sched_barrier(0);                                               \
    gcompute(As[bufc], Bs[bufc]);                                                    \
    if ((t) + 2 < 32) GSTAGE(bufn, ((t) + 2) * 32);                                  \
  } while (0)

  for (int base = 0; base < 30; base += 3) {
    GTILE(0, 2, base);
    GTILE(1, 0, base + 1);
    GTILE(2, 1, base + 2);
  }
  GTILE(0, 2, 30);
  GTILE(1, 0, 31);
#undef GTILE
#undef GSTAGE

#pragma unroll
  for (int m = 0; m < 4; ++m) {
#pragma unroll
    for (int n = 0; n < 4; ++n) {
      int gc = col0 + wc * 64 + n * 16 + ll;
      int gr0 = row0 + wr * 64 + m * 16 + (lg << 2);
      if (MODE == 0) {
#pragma unroll
        for (int j = 0; j < 4; ++j)
          ((float*)C)[(size_t)(gr0 + j) * N + gc] = acc[m][n][j] + bias[gc];
      } else {
        if (gc < 2048) {
          float sc = (gc < 1024) ? QSCALE_LOG2E : 1.0f;
#pragma unroll
          for (int j = 0; j < 4; ++j)
            ((ushort_t*)C)[(size_t)(gr0 + j) * 2048 + gc] = f2bf(acc[m][n][j] * sc);
        } else {
          // V columns -> transposed store, 4 consecutive n packed into 8B
          int hv = (gc - 2048) >> 6, dv = (gc - 2048) & 63;
          int bb = gr0 >> 11, nn = gr0 & 2047;
          uint2 w;
          w.x = cvtpk(acc[m][n][0], acc[m][n][1]);
          w.y = cvtpk(acc[m][n][2], acc[m][n][3]);
          *(uint2*)(vt_out + ((size_t)((bb * 16 + hv) * 64 + dv)) * 2048 + nn) = w;
        }
      }
    }
  }
}

// ---------------- differential flash attention (QBLK=128, 8 waves, counted-vmcnt pipeline) ----------------
// R16 kernel, UNCHANGED (proven 84.7us): triple-buffered K/V + raw s_barrier
// with counted vmcnt (never 0 in steady state), sequential passes, shared
// per-wave P (affine stride 72).
__global__ __launch_bounds__(512) void diff_attn(const ushort_t* __restrict__ qk,
                                                 const ushort_t* __restrict__ vt,
                                                 ushort_t* __restrict__ o,
                                                 const float* __restrict__ lq1,
                                                 const float* __restrict__ lk1,
                                                 const float* __restrict__ lq2,
                                                 const float* __restrict__ lk2,
                                                 const float* __restrict__ subln) {
  const int lin = blockIdx.x + (blockIdx.y << 4) + (blockIdx.z << 8);
  const int swz = ((lin & 7) << 6) + (lin >> 3);    // XCD r -> swz in [64r, 64r+64)
  const int qt = swz & 15, h = (swz >> 4) & 15, b = swz >> 8;
  const int tid = threadIdx.x, wave = tid >> 6, lane = tid & 63;
  const int lg = lane >> 4, ll = lane & 15;

  const size_t qbase = (size_t)b * 2048 * 2048;
  const int cq1 = (h << 5), cq2 = 512 + (h << 5);
  const int ck1 = 1024 + (h << 5), ck2 = 1536 + (h << 5);
  const size_t vbase = (size_t)((b * 16 + h) * 64) * 2048;

  float sl1 = 0.f, sl2 = 0.f;
  for (int j = 0; j < 32; ++j) { sl1 += lq1[j] * lk1[j]; sl2 += lq2[j] * lk2[j]; }
  const float lam = __expf(sl1) - __expf(sl2) + LAMBDA_INIT;

  __shared__ ushort_t Ks[3][64 * 64];   // triple buffer, XOR-8 swizzled
  __shared__ ushort_t Vs[3][64 * 64];   // triple buffer, XOR-8 swizzled
  __shared__ ushort_t Pl[8][16 * 72];   // per-wave shared P (stride 72, proven affine)

  // Q fragments (B-operand of swapped QK^T); this wave owns q-rows qt*128+wave*16..+15
  const int qrow = qt * 128 + wave * 16 + ll;
  const bf16x8 q1f = *(const bf16x8*)(qk + qbase + (size_t)qrow * 2048 + cq1 + (lg << 3));
  const bf16x8 q2f = *(const bf16x8*)(qk + qbase + (size_t)qrow * 2048 + cq2 + (lg << 3));

  f32x4 o1[4], o2[4];
#pragma unroll
  for (int nb = 0; nb < 4; ++nb) { o1[nb] = zero4(); o2[nb] = zero4(); }
  float l1p = 0.f, l2p = 0.f;
  ushort_t* Pw = &Pl[wave][0];

  // staging: 512 threads, ONE 16B K-slot + ONE 16B V-slot each.
  // slot s=tid -> row r = s>>3, lds chunk s&7 holds global chunk (s&7)^(r&7)
  const int r0 = tid >> 3, c0 = (tid & 7) ^ (r0 & 7);
  const int kc0 = ((c0 & 4) ? ck2 : ck1) + ((c0 & 3) << 3);
  const int ub0 = tid << 4;

#define STAGE(buf, kv0)                                                                   \
  do {                                                                                    \
    gload_lds16(qk + qbase + (size_t)((kv0) + r0) * 2048 + kc0, (char*)Ks[buf] + ub0);    \
    gload_lds16(vt + vbase + (size_t)r0 * 2048 + (kv0) + (c0 << 3), (char*)Vs[buf] + ub0);\
  } while (0)

  auto compute_tile = [&](const ushort_t* Kc, const ushort_t* Vc) {
    bf16x8 vf[2][4];
#pragma unroll
    for (int ks = 0; ks < 2; ++ks)
#pragma unroll
      for (int nb = 0; nb < 4; ++nb)
        vf[ks][nb] = *(const bf16x8*)(Vc + nb * 1024 + ll * 64 + (((ks * 4 + lg) ^ (ll & 7)) << 3));
#pragma unroll
    for (int pass = 0; pass < 2; ++pass) {
      const int cK = (lg ^ (ll & 7)) ^ (pass << 2);
      bf16x8 kf[4];
#pragma unroll
      for (int nb = 0; nb < 4; ++nb)
        kf[nb] = *(const bf16x8*)(Kc + nb * 1024 + ll * 64 + (cK << 3));
      const bf16x8 qf = pass ? q2f : q1f;
      f32x4* oacc = pass ? o2 : o1;
      f32x4 s[4];
      __builtin_amdgcn_s_setprio(1);
#pragma unroll
      for (int nb = 0; nb < 4; ++nb)
        s[nb] = mfma16(kf[nb], qf, zero4());   // D: row=k (4lg+i), col=q (ll)
      __builtin_amdgcn_s_setprio(0);
      float part = 0.f;
#pragma unroll
      for (int nb = 0; nb < 4; ++nb) {
        float e0 = fexp2(s[nb][0]), e1 = fexp2(s[nb][1]);
        float e2 = fexp2(s[nb][2]), e3 = fexp2(s[nb][3]);
        part += (e0 + e1) + (e2 + e3);
        uint2 w;
        w.x = cvtpk(e0, e1);
        w.y = cvtpk(e2, e3);
        // P[q=ll][k = nb*16 + 4lg .. +3]
        *(uint2*)(Pw + ll * 72 + nb * 16 + (lg << 2)) = w;
      }
      if (pass) l2p += part; else l1p += part;
      __builtin_amdgcn_s_setprio(1);
#pragma unroll
      for (int ks = 0; ks < 2; ++ks) {
        bf16x8 pf = *(const bf16x8*)(Pw + ll * 72 + ks * 32 + (lg << 3));
#pragma unroll
        for (int nb = 0; nb < 4; ++nb) oacc[nb] = mfma16(pf, vf[ks][nb], oacc[nb]);
      }
      __builtin_amdgcn_s_setprio(0);
    }
  };

  // prologue: two tiles in flight
  STAGE(0, 0);
  STAGE(1, 64);

#define TILE(bufc, bufn, t)                                                               \
  do {                                                                                    \
    if ((t) < 31) asm volatile("s_waitcnt vmcnt(2)" ::: "memory");                        \
    else          asm volatile("s_waitcnt vmcnt(0)" ::: "memory");                        \
    __builtin_amdgcn_s_barrier();                                                         \
    __builtin_amdgcn_sched_barrier(0);                                                    \
    compute_tile(Ks[bufc], Vs[bufc]);                                                     \
    if ((t) + 2 < 32) STAGE(bufn, ((t) + 2) * 64);                                        \
  } while (0)

  for (int base = 0; base < 30; base += 3) {
    TILE(0, 2, base);
    TILE(1, 0, base + 1);
    TILE(2, 1, base + 2);
  }
  TILE(0, 2, 30);
  TILE(1, 0, 31);
#undef TILE
#undef STAGE

  // l lives per-lane for q = ll; finish reduction over lg, then fetch per-row.
  float l1 = l1p; l1 += __shfl_xor(l1, 16); l1 += __shfl_xor(l1, 32);
  float l2 = l2p; l2 += __shfl_xor(l2, 16); l2 += __shfl_xor(l2, 32);
  float i1[4], i2[4];
#pragma unroll
  for (int j = 0; j < 4; ++j) {
    int src = (lane & 48) | ((lg << 2) + j);   // lane with ll == q-row
    i1[j] = 1.f / __shfl(l1, src);
    i2[j] = 1.f / __shfl(l2, src);
  }

  float ss[4] = {0.f, 0.f, 0.f, 0.f};
  f32x4 ov[4];
#pragma unroll
  for (int nb = 0; nb < 4; ++nb) {
#pragma unroll
    for (int j = 0; j < 4; ++j) {
      float x = o1[nb][j] * i1[j] - lam * (o2[nb][j] * i2[j]);
      ov[nb][j] = x;
      ss[j] += x * x;
    }
  }
#pragma unroll
  for (int mask = 1; mask < 16; mask <<= 1)
#pragma unroll
    for (int j = 0; j < 4; ++j) ss[j] += __shfl_xor(ss[j], mask);
  float nf[4];
#pragma unroll
  for (int j = 0; j < 4; ++j) nf[j] = rsqrtf(ss[j] * (1.f / 64.f) + 1e-5f);
  const size_t orow0 = (size_t)(b * 2048 + qt * 128 + wave * 16);
#pragma unroll
  for (int nb = 0; nb < 4; ++nb) {
    int d = nb * 16 + ll;
    float sw = subln[d] * ONE_MINUS_LI;
#pragma unroll
    for (int j = 0; j < 4; ++j) {
      int r = (lg << 2) + j;
      o[(orow0 + r) * 1024 + (h << 6) + d] = f2bf(ov[nb][j] * nf[j] * sw);
    }
  }
}

extern "C" void kernel_launch(void* const* d_in, const int* in_sizes, int n_in,
                              void* d_out, int out_size, void* d_ws, size_t ws_size,
                              hipStream_t stream) {
  const float* x      = (const float*)d_in[0];
  const float* W_qkv  = (const float*)d_in[1];
  const float* W_proj = (const float*)d_in[2];
  const float* b_proj = (const float*)d_in[3];
  const float* lq1    = (const float*)d_in[4];
  const float* lk1    = (const float*)d_in[5];
  const float* lq2    = (const float*)d_in[6];
  const float* lk2    = (const float*)d_in[7];
  const float* subln  = (const float*)d_in[8];

  char* ws = (char*)d_ws;
  ushort_t* xb     = (ushort_t*)(ws);                 //  8,388,608 B (4096x1024 bf16)
  ushort_t* qkb    = (ushort_t*)(ws + 8388608);       // 16,777,216 B (4096x2048 bf16, q|k)
  ushort_t* vtb    = (ushort_t*)(ws + 25165824);      //  8,388,608 B (V^T: [2*16*64][2048])
  ushort_t* wqkvT  = (ushort_t*)(ws + 33554432);      //  6,291,456 B (3072x1024 bf16)
  ushort_t* wprojT = (ushort_t*)(ws + 39845888);      //  2,097,152 B (1024x1024 bf16)
  ushort_t* ob     = (ushort_t*)(ws + 41943040);      //  8,388,608 B (4096x1024 bf16)

  prep<<<6144, 256, 0, stream>>>(x, xb, W_qkv, wqkvT, W_proj, wprojT);
  gemm_bt<1><<<dim3(32, 24), 256, 0, stream>>>(xb, wqkvT, (void*)qkb, vtb, nullptr, 4096, 3072, 1024);
  diff_attn<<<dim3(16, 16, 2), 512, 0, stream>>>(qkb, vtb, ob, lq1, lk1, lq2, lk2, subln);
  gemm_bt<0><<<dim3(32, 8), 256, 0, stream>>>(ob, wprojT, d_out, nullptr, b_proj, 4096, 1024, 1024);
}